// Round 13
// baseline (385.348 us; speedup 1.0000x reference)
//
#include <hip/hip_runtime.h>
#include <stdint.h>
#include <stddef.h>

typedef __attribute__((ext_vector_type(8))) short short8;
typedef __attribute__((ext_vector_type(4))) float f32x4;

// ---- sizes ----
// x: (8, 64, 32, 32, 96) f32.  NH=4, hd=16, scale = 0.25
// intermediates q,k,v: bf16, per (b,o): d-plane layout [d=0..95][pos=h*32+w] (2KB planes)
#define PER_BO 98304            // 96 d * 1024 pos ushorts per (b,o)

__device__ __forceinline__ unsigned int cvtpk(float lo, float hi) {
    unsigned int r;
    asm("v_cvt_pk_bf16_f32 %0, %1, %2" : "=v"(r) : "v"(lo), "v"(hi));
    return r;
}

// ============================ Kernel 1: projection GEMM (MFMA) ============================
// Block = (b, h-row, d-group of 16): M = 32 w x 16 dd = 512, N = 192, K = 64.
// 1024 threads (16 waves, 2 m-tiles each). m = w*16+dd => every A-load wave-op is 4 aligned
// full 64B lines, and each x-line is read by EXACTLY ONE block (perfect read partition).
// Every output 64B line (32 w at fixed o,d) fully produced in-block. Cb double-buffered,
// 12 barriers. launch_bounds(1024,8) -> VGPR<=64 -> 2 blocks/CU = 32 waves (full occupancy).
__global__ __launch_bounds__(1024, 8) void proj_mfma(
    const float* __restrict__ x, const float* __restrict__ w_sr, const float* __restrict__ b_sr,
    const float* __restrict__ Wq, const float* __restrict__ bq,
    const float* __restrict__ Wkv, const float* __restrict__ bkv,
    unsigned short* __restrict__ qb, unsigned short* __restrict__ kb, unsigned short* __restrict__ vb)
{
    __shared__ unsigned short Wh[12288];
    __shared__ float bl[192];
    __shared__ unsigned short Cb[2 * 8256];   // [buf][o_l: stride 516][m: 512]

    int t = threadIdx.x;
    int bidx = blockIdx.x;
    int b = bidx & 7;
    int r2 = bidx >> 3;
    int hrow = r2 & 31;                // 0..31
    int dg = r2 >> 5;                  // 0..5 (d-group of 16)

    int lane = t & 63;
    int wvi = t >> 6;                  // 0..15; wave owns m-tiles wvi*2, wvi*2+1 (tile == w)
    int lr = lane & 15, hk = lane >> 4;

    // ---- A: load x straight into registers; each wave-op = 4 aligned 64B lines ----
    const float* xb = x + (size_t)b * 6291456 + hrow * 3072 + dg * 16;
    float af[2][16];
#pragma unroll
    for (int pi = 0; pi < 2; ++pi) {
        int w = wvi * 2 + pi;
        const float* xp = xb + (size_t)(hk * 8) * 98304 + w * 96 + lr;
#pragma unroll
        for (int j = 0; j < 8; ++j) {
            af[pi][j]     = xp[(size_t)j * 98304];
            af[pi][8 + j] = xp[(size_t)(32 + j) * 98304];
        }
    }

    // ---- stage W_eff (bf16, swizzled) ----
#pragma unroll
    for (int i = 0; i < 3; ++i) {
        int qi = t + i * 1024;         // quad index, 3072 total
        int o = qi >> 4;
        int cq = qi & 15;
        int c = cq * 4;
        float4 wv4;
        if (o < 64) wv4 = *reinterpret_cast<const float4*>(Wq + o * 64 + c);
        else {
            wv4 = *reinterpret_cast<const float4*>(Wkv + (o - 64) * 64 + c);
            float4 sr = *reinterpret_cast<const float4*>(w_sr + c);
            wv4.x *= sr.x; wv4.y *= sr.y; wv4.z *= sr.z; wv4.w *= sr.w;
        }
        uint2 pk; pk.x = cvtpk(wv4.x, wv4.y); pk.y = cvtpk(wv4.z, wv4.w);
        int sw = (cq >> 1) ^ (o & 7);
        *reinterpret_cast<uint2*>(&Wh[o * 64 + sw * 8 + (cq & 1) * 4]) = pk;
    }
    if (t < 192) {
        float s;
        if (t < 64) s = bq[t];
        else {
            s = bkv[t - 64];
            for (int c = 0; c < 64; ++c) s += Wkv[(t - 64) * 64 + c] * b_sr[c];
        }
        bl[t] = s;
    }
    __syncthreads();

    // ---- convert A to hi/lo bf16 fragments ----
    short8 ahf[2][2], alf[2][2];
#pragma unroll
    for (int pi = 0; pi < 2; ++pi) {
#pragma unroll
        for (int half = 0; half < 2; ++half) {
            union { unsigned int u[4]; short8 v; } H, L;
#pragma unroll
            for (int q = 0; q < 4; ++q) {
                float f0 = af[pi][half * 8 + 2 * q];
                float f1 = af[pi][half * 8 + 2 * q + 1];
                unsigned int hp = cvtpk(f0, f1);
                float h0 = __uint_as_float(hp << 16);
                float h1 = __uint_as_float(hp & 0xffff0000u);
                H.u[q] = hp;
                L.u[q] = cvtpk(f0 - h0, f1 - h1);
            }
            ahf[pi][half] = H.v; alf[pi][half] = L.v;
        }
    }

    // ---- Cb write offsets: rows m0..m0+3 = consecutive dd -> uint2 ----
    int wo[2];
#pragma unroll
    for (int pi = 0; pi < 2; ++pi)
        wo[pi] = lr * 516 + (wvi * 2 + pi) * 16 + hk * 4;

    // ---- stream-out decode: 1 unit/thread = 8 w at fixed (o_l, dd) = 16B ----
    int o_l = t >> 6;
    int dd  = (t >> 2) & 15;
    int w8  = t & 3;
    size_t so_po = (size_t)o_l * PER_BO + (size_t)(dg * 16 + dd) * 1024 + hrow * 32 + w8 * 8;
    int so_lo = o_l * 516 + w8 * 128 + dd;     // + k*16, k=0..7

    float biasv[12];
#pragma unroll
    for (int ot = 0; ot < 12; ++ot) biasv[ot] = bl[ot * 16 + lr];

    f32x4 zero4 = {0.f, 0.f, 0.f, 0.f};
    int s7 = lr & 7;

#pragma unroll
    for (int ot = 0; ot < 12; ++ot) {
        unsigned short* cb = Cb + (ot & 1) * 8256;
        {
            int o = ot * 16 + lr;
            const unsigned short* wr = &Wh[o * 64];
            short8 b0 = *reinterpret_cast<const short8*>(wr + ((hk ^ s7) * 8));
            short8 b1 = *reinterpret_cast<const short8*>(wr + (((hk + 4) ^ s7) * 8));
            float bo = biasv[ot];
#pragma unroll
            for (int pi = 0; pi < 2; ++pi) {
                f32x4 acc = __builtin_amdgcn_mfma_f32_16x16x32_bf16(ahf[pi][0], b0, zero4, 0, 0, 0);
                acc = __builtin_amdgcn_mfma_f32_16x16x32_bf16(ahf[pi][1], b1, acc, 0, 0, 0);
                acc = __builtin_amdgcn_mfma_f32_16x16x32_bf16(alf[pi][0], b0, acc, 0, 0, 0);
                acc = __builtin_amdgcn_mfma_f32_16x16x32_bf16(alf[pi][1], b1, acc, 0, 0, 0);
                uint2 st;
                st.x = cvtpk(acc[0] + bo, acc[1] + bo);
                st.y = cvtpk(acc[2] + bo, acc[3] + bo);
                *reinterpret_cast<uint2*>(&cb[wo[pi]]) = st;
            }
        }
        __syncthreads();
        {
            int sel = ot >> 2;
            unsigned short* base =
                (sel == 0 ? qb : (sel == 1 ? kb : vb)) + (size_t)(b * 64 + (ot & 3) * 16) * PER_BO;
            union { unsigned short e[8]; uint4 v; } pk;
#pragma unroll
            for (int k = 0; k < 8; ++k) pk.e[k] = cb[so_lo + k * 16];
            *reinterpret_cast<uint4*>(base + so_po) = pk.v;
        }
    }
}

// ============================ Kernel 2: attention (direct-reg, d-planes) ============================
// Verbatim R9/R12 structure (measured ~122us): zero-barrier pass1 with direct coalesced frag
// reads, wave-private pass2 (V LDS transpose, no barriers), paired 64B out stores.
__global__ __launch_bounds__(512, 4) void attn_kernel(
    const unsigned short* __restrict__ qb, const unsigned short* __restrict__ kb,
    const unsigned short* __restrict__ vb,
    const float* __restrict__ gamma, const float* __restrict__ beta,
    float* __restrict__ out)
{
    __shared__ char smem[61440];
    unsigned short* Vw = (unsigned short*)smem;            // per-wave [w:32][h: stride 36]
    unsigned short* Pb = (unsigned short*)(smem + 18432);
    float* Osf  = (float*)(smem + 27648);                  // 2 bufs x 8 planes x 528
    float* lred = (float*)(smem + 27648);
    float* rlb  = (float*)(smem + 27648 + 16896);

    int t = threadIdx.x;
    int l = t & 63;
    int dsub = t >> 6;
    int lr = l & 15, hk = l >> 4;

    // XCD pair swizzle (both halves of (b,oc) on same XCD, concurrent)
    int id = blockIdx.x;
    int xcd = id & 7;
    int k7 = id >> 3;
    int p = xcd + 8 * (k7 >> 1);
    int half = k7 & 1;
    int oc = p & 63;
    int b = p >> 6;
    int n = oc >> 4;

    const unsigned short* qp = qb + (size_t)(b * 64 + oc) * PER_BO;
    const unsigned short* kp = kb + (size_t)(b * 64 + oc) * PER_BO;
    const unsigned short* vp = vb + (size_t)(b * 64 + oc) * PER_BO;

    float gm = gamma[n], bt = beta[n];
    float decv[8];
#pragma unroll
    for (int gb = 0; gb < 2; ++gb)
#pragma unroll
        for (int r = 0; r < 4; ++r) {
            int hh = half * 16 + hk * 4 + r;
            int gg = gb * 16 + lr;
            float dc = 2.0f * fabsf((float)(hh - gg)) * gm + bt;
            float sp = fmaxf(dc, 0.0f) + log1pf(__expf(-fabsf(dc)));
            decv[gb * 4 + r] = __expf(-sp);
        }

    const float scale = 0.25f;
    f32x4 zero4 = {0.f, 0.f, 0.f, 0.f};

    unsigned int ep[48];
    float lacc[8] = {0.f, 0.f, 0.f, 0.f, 0.f, 0.f, 0.f, 0.f};

    // ---------------- PASS 1: direct-reg QK^T -> E + partial l (no LDS, no barriers) ----------------
    int qoff  = half * 512 + lr * 32 + hk * 8;
    int koff0 = lr * 32 + hk * 8;
    int koff1 = koff0 + 512;

    uint4 qv[2], k0v[2], k1v[2];
    {
        int b0p = dsub * 1024;
        qv[0]  = *reinterpret_cast<const uint4*>(qp + b0p + qoff);
        k0v[0] = *reinterpret_cast<const uint4*>(kp + b0p + koff0);
        k1v[0] = *reinterpret_cast<const uint4*>(kp + b0p + koff1);
        int b1p = (8 + dsub) * 1024;
        qv[1]  = *reinterpret_cast<const uint4*>(qp + b1p + qoff);
        k0v[1] = *reinterpret_cast<const uint4*>(kp + b1p + koff0);
        k1v[1] = *reinterpret_cast<const uint4*>(kp + b1p + koff1);
    }

#pragma unroll
    for (int ch = 0; ch < 12; ++ch) {
        int s = ch & 1;
        union { uint4 u; short8 v; } A, B0, B1;
        A.u = qv[s]; B0.u = k0v[s]; B1.u = k1v[s];
        f32x4 s0 = __builtin_amdgcn_mfma_f32_16x16x32_bf16(A.v, B0.v, zero4, 0, 0, 0);
        f32x4 s1 = __builtin_amdgcn_mfma_f32_16x16x32_bf16(A.v, B1.v, zero4, 0, 0, 0);
        if (ch < 10) {
            int bp = ((ch + 2) * 8 + dsub) * 1024;
            qv[s]  = *reinterpret_cast<const uint4*>(qp + bp + qoff);
            k0v[s] = *reinterpret_cast<const uint4*>(kp + bp + koff0);
            k1v[s] = *reinterpret_cast<const uint4*>(kp + bp + koff1);
        }
        float e[8];
#pragma unroll
        for (int r = 0; r < 4; ++r) {
            e[r]     = __expf(s0[r] * scale + decv[r]);
            e[4 + r] = __expf(s1[r] * scale + decv[4 + r]);
        }
#pragma unroll
        for (int i = 0; i < 8; ++i) lacc[i] += e[i];
        ep[ch * 4 + 0] = cvtpk(e[0], e[1]);
        ep[ch * 4 + 1] = cvtpk(e[2], e[3]);
        ep[ch * 4 + 2] = cvtpk(e[4], e[5]);
        ep[ch * 4 + 3] = cvtpk(e[6], e[7]);
    }

    // ---------------- l reduction (only cross-wave communication) ----------------
#pragma unroll
    for (int i = 0; i < 8; ++i)
        lred[dsub * 528 + (hk * 4 + (i & 3)) * 33 + (i >> 2) * 16 + lr] = lacc[i];
    __syncthreads();
    {
        float rsum = 0.f;
#pragma unroll
        for (int s = 0; s < 8; ++s) rsum += lred[s * 528 + (t >> 5) * 33 + (t & 31)];
        rlb[(t >> 5) * 33 + (t & 31)] = 1.0f / rsum;
    }
    __syncthreads();
    float rl8[8];
#pragma unroll
    for (int i = 0; i < 8; ++i)
        rl8[i] = rlb[(hk * 4 + (i & 3)) * 33 + (i >> 2) * 16 + lr];
    __syncthreads();

    // ---------------- PASS 2: wave-private V stage + P -> PV -> out ----------------
    int vgoff = l * 16;
    int vwbase = dsub * 1152 + ((l & 1) * 16) * 36 + (l >> 1);
    unsigned short* Pw = Pb + dsub * 576;

    uint4 vv0[2], vv1[2];
    {
        int b0p = dsub * 1024 + vgoff;
        vv0[0] = *reinterpret_cast<const uint4*>(vp + b0p);
        vv1[0] = *reinterpret_cast<const uint4*>(vp + b0p + 8);
        int b1p = (8 + dsub) * 1024 + vgoff;
        vv0[1] = *reinterpret_cast<const uint4*>(vp + b1p);
        vv1[1] = *reinterpret_cast<const uint4*>(vp + b1p + 8);
    }

    size_t obase0 = ((size_t)(b * 64 + oc) * 1024 + half * 512 + t) * 96;

#pragma unroll
    for (int ch = 0; ch < 12; ++ch) {
        int s = ch & 1;
        {
            union { uint4 u; unsigned short e[8]; } V0, V1;
            V0.u = vv0[s]; V1.u = vv1[s];
#pragma unroll
            for (int i = 0; i < 8; ++i) Vw[vwbase + i * 36] = V0.e[i];
#pragma unroll
            for (int i = 0; i < 8; ++i) Vw[vwbase + (i + 8) * 36] = V1.e[i];
        }
#pragma unroll
        for (int gb = 0; gb < 2; ++gb)
#pragma unroll
            for (int rp = 0; rp < 2; ++rp) {
                unsigned int u = ep[ch * 4 + gb * 2 + rp];
                float p0 = __uint_as_float(u << 16)         * rl8[gb * 4 + rp * 2];
                float p1 = __uint_as_float(u & 0xffff0000u) * rl8[gb * 4 + rp * 2 + 1];
                unsigned int pk = cvtpk(p0, p1);
                Pw[(hk * 4 + rp * 2) * 36 + gb * 16 + lr]     = (unsigned short)pk;
                Pw[(hk * 4 + rp * 2 + 1) * 36 + gb * 16 + lr] = (unsigned short)(pk >> 16);
            }
        if (ch < 10) {
            int bp = ((ch + 2) * 8 + dsub) * 1024 + vgoff;
            vv0[s] = *reinterpret_cast<const uint4*>(vp + bp);
            vv1[s] = *reinterpret_cast<const uint4*>(vp + bp + 8);
        }
        asm volatile("s_waitcnt lgkmcnt(0)" ::: "memory");
        __builtin_amdgcn_sched_barrier(0);
        short8 pa  = *reinterpret_cast<const short8*>(Pw + lr * 36 + hk * 8);
        short8 vb0 = *reinterpret_cast<const short8*>(Vw + dsub * 1152 + lr * 36 + hk * 8);
        short8 vb1 = *reinterpret_cast<const short8*>(Vw + dsub * 1152 + (16 + lr) * 36 + hk * 8);
        f32x4 o0 = __builtin_amdgcn_mfma_f32_16x16x32_bf16(pa, vb0, zero4, 0, 0, 0);
        f32x4 o1 = __builtin_amdgcn_mfma_f32_16x16x32_bf16(pa, vb1, zero4, 0, 0, 0);
        float* Od = Osf + s * 4224 + dsub * 528;
#pragma unroll
        for (int r = 0; r < 4; ++r) {
            Od[(hk * 4 + r) * 33 + lr]      = o0[r];
            Od[(hk * 4 + r) * 33 + 16 + lr] = o1[r];
        }
        if (ch & 1) {
            __syncthreads();
            int lidx = (t >> 5) * 33 + (t & 31);
            float4 q0, q1, q2, q3;
            q0.x = Osf[0 * 528 + lidx]; q0.y = Osf[1 * 528 + lidx];
            q0.z = Osf[2 * 528 + lidx]; q0.w = Osf[3 * 528 + lidx];
            q1.x = Osf[4 * 528 + lidx]; q1.y = Osf[5 * 528 + lidx];
            q1.z = Osf[6 * 528 + lidx]; q1.w = Osf[7 * 528 + lidx];
            q2.x = Osf[4224 + 0 * 528 + lidx]; q2.y = Osf[4224 + 1 * 528 + lidx];
            q2.z = Osf[4224 + 2 * 528 + lidx]; q2.w = Osf[4224 + 3 * 528 + lidx];
            q3.x = Osf[4224 + 4 * 528 + lidx]; q3.y = Osf[4224 + 5 * 528 + lidx];
            q3.z = Osf[4224 + 6 * 528 + lidx]; q3.w = Osf[4224 + 7 * 528 + lidx];
            float* po = out + obase0 + (ch >> 1) * 16;
            *reinterpret_cast<float4*>(po)      = q0;
            *reinterpret_cast<float4*>(po + 4)  = q1;
            *reinterpret_cast<float4*>(po + 8)  = q2;
            *reinterpret_cast<float4*>(po + 12) = q3;
            __syncthreads();
        }
    }
}

extern "C" void kernel_launch(void* const* d_in, const int* in_sizes, int n_in,
                              void* d_out, int out_size, void* d_ws, size_t ws_size,
                              hipStream_t stream) {
    const float* x     = (const float*)d_in[0];
    const float* w_sr  = (const float*)d_in[1];
    const float* b_sr  = (const float*)d_in[2];
    const float* Wq    = (const float*)d_in[3];
    const float* bq    = (const float*)d_in[4];
    const float* Wkv   = (const float*)d_in[5];
    const float* bkv   = (const float*)d_in[6];
    const float* gamma = (const float*)d_in[7];
    const float* beta  = (const float*)d_in[8];
    float* out = (float*)d_out;

    unsigned short* qb = (unsigned short*)d_ws;
    unsigned short* kb = qb + (size_t)50331648;
    unsigned short* vb = kb + (size_t)50331648;

    proj_mfma<<<1536, 1024, 0, stream>>>(x, w_sr, b_sr, Wq, bq, Wkv, bkv, qb, kb, vb);

    attn_kernel<<<1024, 512, 0, stream>>>(qb, kb, vb, gamma, beta, out);
}

// Round 14
// 384.151 us; speedup vs baseline: 1.0031x; 1.0031x over previous
//
#include <hip/hip_runtime.h>
#include <stdint.h>
#include <stddef.h>

typedef __attribute__((ext_vector_type(8))) short short8;
typedef __attribute__((ext_vector_type(4))) float f32x4;

// ---- sizes ----
// x: (8, 64, 32, 32, 96) f32.  NH=4, hd=16, scale = 0.25
// intermediates q,k,v bf16, per (b,o): PAIR-GRANULE layout:
//   short addr = (b*64+o)*98304 + pp*2048 + pos8*16 + par*8 + (pos&7)
//   where d = 2*pp+par (pp=0..47), pos = h*32+w, pos8 = pos>>3.
//   => 16B granule = 8 consecutive w at fixed d; 128B sector = 32 pos x 2 d (one hrow).
#define PER_BO 98304

__device__ __forceinline__ unsigned int cvtpk(float lo, float hi) {
    unsigned int r;
    asm("v_cvt_pk_bf16_f32 %0, %1, %2" : "=v"(r) : "v"(lo), "v"(hi));
    return r;
}

// ============================ Kernel 1: projection GEMM (MFMA) ============================
// Block = (b, hrow, dg of 16): M = 32 w x 16 dd = 512, aligned 64B A-load segments (R13).
// Decode lf = hrow*6+dg -> dg-siblings sharing x 128B-sectors are dispatch-adjacent on one
// XCD (L2 merge). Stream-out emits the pair-granule layout: full 128B sectors per block,
// 8 x 128B segments per wave-op.
__global__ __launch_bounds__(1024, 8) void proj_mfma(
    const float* __restrict__ x, const float* __restrict__ w_sr, const float* __restrict__ b_sr,
    const float* __restrict__ Wq, const float* __restrict__ bq,
    const float* __restrict__ Wkv, const float* __restrict__ bkv,
    unsigned short* __restrict__ qb, unsigned short* __restrict__ kb, unsigned short* __restrict__ vb)
{
    __shared__ unsigned short Wh[12288];
    __shared__ float bl[192];
    __shared__ unsigned short Cb[2 * 8256];   // [buf][o_l: stride 516][m: 512], m = w*16+dd

    int t = threadIdx.x;
    int bidx = blockIdx.x;
    int b = bidx & 7;
    int lf = bidx >> 3;                // 0..191
    int hrow = lf / 6;
    int dg = lf - hrow * 6;            // 0..5, d-group of 16

    int lane = t & 63;
    int wvi = t >> 6;                  // 0..15; wave owns w = wvi*2, wvi*2+1
    int lr = lane & 15, hk = lane >> 4;

    // ---- A: direct-to-reg; each wave-op = 4 aligned 64B lines ----
    const float* xb = x + (size_t)b * 6291456 + hrow * 3072 + dg * 16;
    float af[2][16];
#pragma unroll
    for (int pi = 0; pi < 2; ++pi) {
        int w = wvi * 2 + pi;
        const float* xp = xb + (size_t)(hk * 8) * 98304 + w * 96 + lr;
#pragma unroll
        for (int j = 0; j < 8; ++j) {
            af[pi][j]     = xp[(size_t)j * 98304];
            af[pi][8 + j] = xp[(size_t)(32 + j) * 98304];
        }
    }

    // ---- stage W_eff (bf16, swizzled) ----
#pragma unroll
    for (int i = 0; i < 3; ++i) {
        int qi = t + i * 1024;
        int o = qi >> 4;
        int cq = qi & 15;
        int c = cq * 4;
        float4 wv4;
        if (o < 64) wv4 = *reinterpret_cast<const float4*>(Wq + o * 64 + c);
        else {
            wv4 = *reinterpret_cast<const float4*>(Wkv + (o - 64) * 64 + c);
            float4 sr = *reinterpret_cast<const float4*>(w_sr + c);
            wv4.x *= sr.x; wv4.y *= sr.y; wv4.z *= sr.z; wv4.w *= sr.w;
        }
        uint2 pk; pk.x = cvtpk(wv4.x, wv4.y); pk.y = cvtpk(wv4.z, wv4.w);
        int sw = (cq >> 1) ^ (o & 7);
        *reinterpret_cast<uint2*>(&Wh[o * 64 + sw * 8 + (cq & 1) * 4]) = pk;
    }
    if (t < 192) {
        float s;
        if (t < 64) s = bq[t];
        else {
            s = bkv[t - 64];
            for (int c = 0; c < 64; ++c) s += Wkv[(t - 64) * 64 + c] * b_sr[c];
        }
        bl[t] = s;
    }
    __syncthreads();

    // ---- convert A to hi/lo bf16 fragments ----
    short8 ahf[2][2], alf[2][2];
#pragma unroll
    for (int pi = 0; pi < 2; ++pi) {
#pragma unroll
        for (int half = 0; half < 2; ++half) {
            union { unsigned int u[4]; short8 v; } H, L;
#pragma unroll
            for (int q = 0; q < 4; ++q) {
                float f0 = af[pi][half * 8 + 2 * q];
                float f1 = af[pi][half * 8 + 2 * q + 1];
                unsigned int hp = cvtpk(f0, f1);
                float h0 = __uint_as_float(hp << 16);
                float h1 = __uint_as_float(hp & 0xffff0000u);
                H.u[q] = hp;
                L.u[q] = cvtpk(f0 - h0, f1 - h1);
            }
            ahf[pi][half] = H.v; alf[pi][half] = L.v;
        }
    }

    // ---- Cb write offsets: rows m0..m0+3 = consecutive dd -> uint2 ----
    int wo[2];
#pragma unroll
    for (int pi = 0; pi < 2; ++pi)
        wo[pi] = lr * 516 + (wvi * 2 + pi) * 16 + hk * 4;

    // ---- stream-out decode: thread -> (o_l, pr, u8); uint4 = 8 shorts of the pair-granule ----
    int o_l = t >> 6;
    int pr  = (t >> 3) & 7;            // pair within dg
    int u8  = t & 7;                   // 8-short unit within the 64-short hrow run
    size_t so_po = (size_t)o_l * PER_BO + (size_t)(dg * 8 + pr) * 2048 + hrow * 64 + u8 * 8;
    int w0 = (u8 >> 1) * 8;            // first w of this unit
    int dd = pr * 2 + (u8 & 1);        // d within dg
    int cblo = o_l * 516 + dd;         // + w*16

    float biasv[12];
#pragma unroll
    for (int ot = 0; ot < 12; ++ot) biasv[ot] = bl[ot * 16 + lr];

    f32x4 zero4 = {0.f, 0.f, 0.f, 0.f};
    int s7 = lr & 7;

#pragma unroll
    for (int ot = 0; ot < 12; ++ot) {
        unsigned short* cb = Cb + (ot & 1) * 8256;
        {
            int o = ot * 16 + lr;
            const unsigned short* wr = &Wh[o * 64];
            short8 b0 = *reinterpret_cast<const short8*>(wr + ((hk ^ s7) * 8));
            short8 b1 = *reinterpret_cast<const short8*>(wr + (((hk + 4) ^ s7) * 8));
            float bo = biasv[ot];
#pragma unroll
            for (int pi = 0; pi < 2; ++pi) {
                f32x4 acc = __builtin_amdgcn_mfma_f32_16x16x32_bf16(ahf[pi][0], b0, zero4, 0, 0, 0);
                acc = __builtin_amdgcn_mfma_f32_16x16x32_bf16(ahf[pi][1], b1, acc, 0, 0, 0);
                acc = __builtin_amdgcn_mfma_f32_16x16x32_bf16(alf[pi][0], b0, acc, 0, 0, 0);
                acc = __builtin_amdgcn_mfma_f32_16x16x32_bf16(alf[pi][1], b1, acc, 0, 0, 0);
                uint2 st;
                st.x = cvtpk(acc[0] + bo, acc[1] + bo);
                st.y = cvtpk(acc[2] + bo, acc[3] + bo);
                *reinterpret_cast<uint2*>(&cb[wo[pi]]) = st;
            }
        }
        __syncthreads();
        {
            int sel = ot >> 2;
            unsigned short* base =
                (sel == 0 ? qb : (sel == 1 ? kb : vb)) + (size_t)(b * 64 + (ot & 3) * 16) * PER_BO;
            union { unsigned short e[8]; uint4 v; } pk;
#pragma unroll
            for (int i = 0; i < 8; ++i) pk.e[i] = cb[cblo + (w0 + i) * 16];
            *reinterpret_cast<uint4*>(base + so_po) = pk.v;
        }
    }
}

// ============================ Kernel 2: attention (pair-granule, d-pair waves) ============================
// Zero-barrier pass1: frags load directly (1 uint4 = 8 w at fixed d), wave dsub owns pairs
// pp = j*8+dsub (j=0..5, d = 16j+2dsub+par). Pass2 wave-private; out 64B/thread per j.
// LDS 79872 dynamic (2 blocks/CU): Vw 8x2304 @0 (lred/rlb alias), Pb 8x576 @36864, Osf 16x528 @46080.
__global__ __launch_bounds__(512, 4) void attn_kernel(
    const unsigned short* __restrict__ qb, const unsigned short* __restrict__ kb,
    const unsigned short* __restrict__ vb,
    const float* __restrict__ gamma, const float* __restrict__ beta,
    float* __restrict__ out)
{
    extern __shared__ char smem[];
    unsigned short* Vw = (unsigned short*)smem;             // [wave][par:1152][w*36+h]
    unsigned short* Pb = (unsigned short*)(smem + 36864);   // [wave][576]
    float* Osf  = (float*)(smem + 46080);                   // 16 planes x 528
    float* lred = (float*)smem;
    float* rlb  = (float*)(smem + 16896);

    int t = threadIdx.x;
    int l = t & 63;
    int dsub = t >> 6;
    int lr = l & 15, hk = l >> 4;

    // XCD pair swizzle (both halves of (b,oc) on same XCD)
    int id = blockIdx.x;
    int xcd = id & 7;
    int k7 = id >> 3;
    int p = xcd + 8 * (k7 >> 1);
    int half = k7 & 1;
    int oc = p & 63;
    int b = p >> 6;
    int n = oc >> 4;

    const unsigned short* qp = qb + (size_t)(b * 64 + oc) * PER_BO;
    const unsigned short* kp = kb + (size_t)(b * 64 + oc) * PER_BO;
    const unsigned short* vp = vb + (size_t)(b * 64 + oc) * PER_BO;

    float gm = gamma[n], bt = beta[n];
    float decv[8];
#pragma unroll
    for (int gb = 0; gb < 2; ++gb)
#pragma unroll
        for (int r = 0; r < 4; ++r) {
            int hh = half * 16 + hk * 4 + r;
            int gg = gb * 16 + lr;
            float dc = 2.0f * fabsf((float)(hh - gg)) * gm + bt;
            float sp = fmaxf(dc, 0.0f) + log1pf(__expf(-fabsf(dc)));
            decv[gb * 4 + r] = __expf(-sp);
        }

    const float scale = 0.25f;
    f32x4 zero4 = {0.f, 0.f, 0.f, 0.f};

    unsigned int ep[48];
    float lacc[8] = {0.f, 0.f, 0.f, 0.f, 0.f, 0.f, 0.f, 0.f};

    // ---------------- PASS 1: direct-frag QK^T -> E + partial l (no LDS, no barriers) ----------------
    int fo = (lr * 4 + hk) * 16;
    int qbase  = half * 1024 + fo;
    int kbase0 = fo;
    int kbase1 = 1024 + fo;

    uint4 qv[2][2], k0v[2][2], k1v[2][2];
#pragma unroll
    for (int s = 0; s < 2; ++s) {
        int po = (s * 8 + dsub) * 2048;
#pragma unroll
        for (int par = 0; par < 2; ++par) {
            qv[s][par]  = *reinterpret_cast<const uint4*>(qp + po + qbase  + par * 8);
            k0v[s][par] = *reinterpret_cast<const uint4*>(kp + po + kbase0 + par * 8);
            k1v[s][par] = *reinterpret_cast<const uint4*>(kp + po + kbase1 + par * 8);
        }
    }

#pragma unroll
    for (int j = 0; j < 6; ++j) {
        int s = j & 1;
#pragma unroll
        for (int par = 0; par < 2; ++par) {
            union { uint4 u; short8 v; } A, B0, B1;
            A.u = qv[s][par]; B0.u = k0v[s][par]; B1.u = k1v[s][par];
            f32x4 s0 = __builtin_amdgcn_mfma_f32_16x16x32_bf16(A.v, B0.v, zero4, 0, 0, 0);
            f32x4 s1 = __builtin_amdgcn_mfma_f32_16x16x32_bf16(A.v, B1.v, zero4, 0, 0, 0);
            float e[8];
#pragma unroll
            for (int r = 0; r < 4; ++r) {
                e[r]     = __expf(s0[r] * scale + decv[r]);
                e[4 + r] = __expf(s1[r] * scale + decv[4 + r]);
            }
#pragma unroll
            for (int i = 0; i < 8; ++i) lacc[i] += e[i];
            ep[j * 8 + par * 4 + 0] = cvtpk(e[0], e[1]);
            ep[j * 8 + par * 4 + 1] = cvtpk(e[2], e[3]);
            ep[j * 8 + par * 4 + 2] = cvtpk(e[4], e[5]);
            ep[j * 8 + par * 4 + 3] = cvtpk(e[6], e[7]);
        }
        if (j < 4) {
            int po = ((j + 2) * 8 + dsub) * 2048;
#pragma unroll
            for (int par = 0; par < 2; ++par) {
                qv[s][par]  = *reinterpret_cast<const uint4*>(qp + po + qbase  + par * 8);
                k0v[s][par] = *reinterpret_cast<const uint4*>(kp + po + kbase0 + par * 8);
                k1v[s][par] = *reinterpret_cast<const uint4*>(kp + po + kbase1 + par * 8);
            }
        }
    }

    // ---------------- l reduction ----------------
#pragma unroll
    for (int i = 0; i < 8; ++i)
        lred[dsub * 528 + (hk * 4 + (i & 3)) * 33 + (i >> 2) * 16 + lr] = lacc[i];
    __syncthreads();
    {
        float rsum = 0.f;
#pragma unroll
        for (int s = 0; s < 8; ++s) rsum += lred[s * 528 + (t >> 5) * 33 + (t & 31)];
        rlb[(t >> 5) * 33 + (t & 31)] = 1.0f / rsum;
    }
    __syncthreads();
    float rl8[8];
#pragma unroll
    for (int i = 0; i < 8; ++i)
        rl8[i] = rlb[(hk * 4 + (i & 3)) * 33 + (i >> 2) * 16 + lr];
    __syncthreads();

    // ---------------- PASS 2: wave-private V stage (both pars) + P -> PV -> out ----------------
    int vq = l >> 1;
    int vwb = dsub * 2304 + (l & 1) * 1152 + ((vq & 3) * 8) * 36 + (vq >> 2);
    unsigned short* Pw = Pb + dsub * 576;

    uint4 vv[2][4];
#pragma unroll
    for (int s = 0; s < 2; ++s) {
        int po = (s * 8 + dsub) * 2048 + l * 8;
#pragma unroll
        for (int c = 0; c < 4; ++c)
            vv[s][c] = *reinterpret_cast<const uint4*>(vp + po + c * 512);
    }

    size_t obase0 = ((size_t)(b * 64 + oc) * 1024 + half * 512 + t) * 96;

#pragma unroll
    for (int j = 0; j < 6; ++j) {
        int s = j & 1;
        // stage V pair-plane (both pars), transposed
#pragma unroll
        for (int c = 0; c < 4; ++c) {
            union { uint4 u; unsigned short e[8]; } V;
            V.u = vv[s][c];
#pragma unroll
            for (int i = 0; i < 8; ++i) Vw[vwb + c * 8 + i * 36] = V.e[i];
        }
        if (j < 4) {
            int po = ((j + 2) * 8 + dsub) * 2048 + l * 8;
#pragma unroll
            for (int c = 0; c < 4; ++c)
                vv[s][c] = *reinterpret_cast<const uint4*>(vp + po + c * 512);
        }
#pragma unroll
        for (int par = 0; par < 2; ++par) {
            // build P for this par
#pragma unroll
            for (int gb = 0; gb < 2; ++gb)
#pragma unroll
                for (int rp = 0; rp < 2; ++rp) {
                    unsigned int u = ep[j * 8 + par * 4 + gb * 2 + rp];
                    float p0 = __uint_as_float(u << 16)         * rl8[gb * 4 + rp * 2];
                    float p1 = __uint_as_float(u & 0xffff0000u) * rl8[gb * 4 + rp * 2 + 1];
                    unsigned int pk = cvtpk(p0, p1);
                    Pw[(hk * 4 + rp * 2) * 36 + gb * 16 + lr]     = (unsigned short)pk;
                    Pw[(hk * 4 + rp * 2 + 1) * 36 + gb * 16 + lr] = (unsigned short)(pk >> 16);
                }
            asm volatile("s_waitcnt lgkmcnt(0)" ::: "memory");
            __builtin_amdgcn_sched_barrier(0);
            short8 pa  = *reinterpret_cast<const short8*>(Pw + lr * 36 + hk * 8);
            const unsigned short* vbase = Vw + dsub * 2304 + par * 1152;
            short8 vb0 = *reinterpret_cast<const short8*>(vbase + lr * 36 + hk * 8);
            short8 vb1 = *reinterpret_cast<const short8*>(vbase + (16 + lr) * 36 + hk * 8);
            f32x4 o0 = __builtin_amdgcn_mfma_f32_16x16x32_bf16(pa, vb0, zero4, 0, 0, 0);
            f32x4 o1 = __builtin_amdgcn_mfma_f32_16x16x32_bf16(pa, vb1, zero4, 0, 0, 0);
            float* Od = Osf + (2 * dsub + par) * 528;
#pragma unroll
            for (int r = 0; r < 4; ++r) {
                Od[(hk * 4 + r) * 33 + lr]      = o0[r];
                Od[(hk * 4 + r) * 33 + 16 + lr] = o1[r];
            }
        }
        __syncthreads();
        {
            int lidx = (t >> 5) * 33 + (t & 31);
            float4 q0, q1, q2, q3;
            q0.x = Osf[0 * 528 + lidx];  q0.y = Osf[1 * 528 + lidx];
            q0.z = Osf[2 * 528 + lidx];  q0.w = Osf[3 * 528 + lidx];
            q1.x = Osf[4 * 528 + lidx];  q1.y = Osf[5 * 528 + lidx];
            q1.z = Osf[6 * 528 + lidx];  q1.w = Osf[7 * 528 + lidx];
            q2.x = Osf[8 * 528 + lidx];  q2.y = Osf[9 * 528 + lidx];
            q2.z = Osf[10 * 528 + lidx]; q2.w = Osf[11 * 528 + lidx];
            q3.x = Osf[12 * 528 + lidx]; q3.y = Osf[13 * 528 + lidx];
            q3.z = Osf[14 * 528 + lidx]; q3.w = Osf[15 * 528 + lidx];
            float* po = out + obase0 + j * 16;
            *reinterpret_cast<float4*>(po)      = q0;
            *reinterpret_cast<float4*>(po + 4)  = q1;
            *reinterpret_cast<float4*>(po + 8)  = q2;
            *reinterpret_cast<float4*>(po + 12) = q3;
        }
        __syncthreads();
    }
}

extern "C" void kernel_launch(void* const* d_in, const int* in_sizes, int n_in,
                              void* d_out, int out_size, void* d_ws, size_t ws_size,
                              hipStream_t stream) {
    const float* x     = (const float*)d_in[0];
    const float* w_sr  = (const float*)d_in[1];
    const float* b_sr  = (const float*)d_in[2];
    const float* Wq    = (const float*)d_in[3];
    const float* bq    = (const float*)d_in[4];
    const float* Wkv   = (const float*)d_in[5];
    const float* bkv   = (const float*)d_in[6];
    const float* gamma = (const float*)d_in[7];
    const float* beta  = (const float*)d_in[8];
    float* out = (float*)d_out;

    unsigned short* qb = (unsigned short*)d_ws;
    unsigned short* kb = qb + (size_t)50331648;
    unsigned short* vb = kb + (size_t)50331648;

    proj_mfma<<<1536, 1024, 0, stream>>>(x, w_sr, b_sr, Wq, bq, Wkv, bkv, qb, kb, vb);

    (void)hipFuncSetAttribute(reinterpret_cast<const void*>(attn_kernel),
                              hipFuncAttributeMaxDynamicSharedMemorySize, 79872);
    attn_kernel<<<1024, 512, 79872, stream>>>(qb, kb, vb, gamma, beta, out);
}

// Round 15
// 292.327 us; speedup vs baseline: 1.3182x; 1.3141x over previous
//
#include <hip/hip_runtime.h>
#include <stdint.h>
#include <stddef.h>

typedef __attribute__((ext_vector_type(8))) short short8;
typedef __attribute__((ext_vector_type(4))) float f32x4;

// ---- sizes ----
// x: (8, 64, 32, 32, 96) f32.  NH=4, hd=16, scale = 0.25
// intermediates q,k,v: bf16, per (b,o): d-plane layout [d=0..95][pos=h*32+w] (2KB planes)
#define PER_BO 98304            // 96 d * 1024 pos ushorts per (b,o)

__device__ __forceinline__ unsigned int cvtpk(float lo, float hi) {
    unsigned int r;
    asm("v_cvt_pk_bf16_f32 %0, %1, %2" : "=v"(r) : "v"(lo), "v"(hi));
    return r;
}

// ============================ Kernel 1: projection GEMM (MFMA) ============================
// Block = (b, hrow, dg of 16): M = 32 w x 16 dd = 512, N = 192, K = 64.
// 1024 threads (16 waves, 2 m-tiles each). m = w*16+dd => every A-load wave-op = 4 aligned
// 64B lines. Decode lf = hrow*6+dg: x-sector mates (dg+-1) at +-1 bidx, output-sector mates
// (hrow+-1) at +-6 bidx -> both inside the 64-block XCD co-residency window -> L2 merge.
// launch_bounds(1024,4): VGPR cap 128 -> NO scratch spills (R13/R14 regression: bounds(,8)
// forced VGPR=32 -> ~250MB spill traffic misread as layout amplification).
__global__ __launch_bounds__(1024, 4) void proj_mfma(
    const float* __restrict__ x, const float* __restrict__ w_sr, const float* __restrict__ b_sr,
    const float* __restrict__ Wq, const float* __restrict__ bq,
    const float* __restrict__ Wkv, const float* __restrict__ bkv,
    unsigned short* __restrict__ qb, unsigned short* __restrict__ kb, unsigned short* __restrict__ vb)
{
    __shared__ unsigned short Wh[12288];
    __shared__ float bl[192];
    __shared__ unsigned short Cb[2 * 8256];   // [buf][o_l: stride 516][m: 512], m = w*16+dd

    int t = threadIdx.x;
    int bidx = blockIdx.x;
    int b = bidx & 7;                  // XCD = b
    int lf = bidx >> 3;                // 0..191
    int hrow = lf / 6;
    int dg = lf - hrow * 6;            // 0..5, d-group of 16

    int lane = t & 63;
    int wvi = t >> 6;                  // 0..15; wave owns w = wvi*2, wvi*2+1
    int lr = lane & 15, hk = lane >> 4;

    // ---- A: direct-to-reg; each wave-op = 4 aligned 64B lines ----
    const float* xb = x + (size_t)b * 6291456 + hrow * 3072 + dg * 16;
    float af[2][16];
#pragma unroll
    for (int pi = 0; pi < 2; ++pi) {
        int w = wvi * 2 + pi;
        const float* xp = xb + (size_t)(hk * 8) * 98304 + w * 96 + lr;
#pragma unroll
        for (int j = 0; j < 8; ++j) {
            af[pi][j]     = xp[(size_t)j * 98304];
            af[pi][8 + j] = xp[(size_t)(32 + j) * 98304];
        }
    }

    // ---- stage W_eff (bf16, swizzled) ----
#pragma unroll
    for (int i = 0; i < 3; ++i) {
        int qi = t + i * 1024;
        int o = qi >> 4;
        int cq = qi & 15;
        int c = cq * 4;
        float4 wv4;
        if (o < 64) wv4 = *reinterpret_cast<const float4*>(Wq + o * 64 + c);
        else {
            wv4 = *reinterpret_cast<const float4*>(Wkv + (o - 64) * 64 + c);
            float4 sr = *reinterpret_cast<const float4*>(w_sr + c);
            wv4.x *= sr.x; wv4.y *= sr.y; wv4.z *= sr.z; wv4.w *= sr.w;
        }
        uint2 pk; pk.x = cvtpk(wv4.x, wv4.y); pk.y = cvtpk(wv4.z, wv4.w);
        int sw = (cq >> 1) ^ (o & 7);
        *reinterpret_cast<uint2*>(&Wh[o * 64 + sw * 8 + (cq & 1) * 4]) = pk;
    }
    if (t < 192) {
        float s;
        if (t < 64) s = bq[t];
        else {
            s = bkv[t - 64];
            for (int c = 0; c < 64; ++c) s += Wkv[(t - 64) * 64 + c] * b_sr[c];
        }
        bl[t] = s;
    }
    __syncthreads();

    // ---- convert A to hi/lo bf16 fragments ----
    short8 ahf[2][2], alf[2][2];
#pragma unroll
    for (int pi = 0; pi < 2; ++pi) {
#pragma unroll
        for (int half = 0; half < 2; ++half) {
            union { unsigned int u[4]; short8 v; } H, L;
#pragma unroll
            for (int q = 0; q < 4; ++q) {
                float f0 = af[pi][half * 8 + 2 * q];
                float f1 = af[pi][half * 8 + 2 * q + 1];
                unsigned int hp = cvtpk(f0, f1);
                float h0 = __uint_as_float(hp << 16);
                float h1 = __uint_as_float(hp & 0xffff0000u);
                H.u[q] = hp;
                L.u[q] = cvtpk(f0 - h0, f1 - h1);
            }
            ahf[pi][half] = H.v; alf[pi][half] = L.v;
        }
    }

    // ---- Cb write offsets: rows m0..m0+3 = consecutive dd -> uint2 ----
    int wo[2];
#pragma unroll
    for (int pi = 0; pi < 2; ++pi)
        wo[pi] = lr * 516 + (wvi * 2 + pi) * 16 + hk * 4;

    // ---- stream-out decode: 1 unit/thread = 8 w at fixed (o_l, dd) = 16B ----
    int o_l = t >> 6;
    int dd  = (t >> 2) & 15;
    int w8  = t & 3;
    size_t so_po = (size_t)o_l * PER_BO + (size_t)(dg * 16 + dd) * 1024 + hrow * 32 + w8 * 8;
    int so_lo = o_l * 516 + w8 * 128 + dd;     // + k*16, k=0..7

    float biasv[12];
#pragma unroll
    for (int ot = 0; ot < 12; ++ot) biasv[ot] = bl[ot * 16 + lr];

    f32x4 zero4 = {0.f, 0.f, 0.f, 0.f};
    int s7 = lr & 7;

#pragma unroll
    for (int ot = 0; ot < 12; ++ot) {
        unsigned short* cb = Cb + (ot & 1) * 8256;
        {
            int o = ot * 16 + lr;
            const unsigned short* wr = &Wh[o * 64];
            short8 b0 = *reinterpret_cast<const short8*>(wr + ((hk ^ s7) * 8));
            short8 b1 = *reinterpret_cast<const short8*>(wr + (((hk + 4) ^ s7) * 8));
            float bo = biasv[ot];
#pragma unroll
            for (int pi = 0; pi < 2; ++pi) {
                f32x4 acc = __builtin_amdgcn_mfma_f32_16x16x32_bf16(ahf[pi][0], b0, zero4, 0, 0, 0);
                acc = __builtin_amdgcn_mfma_f32_16x16x32_bf16(ahf[pi][1], b1, acc, 0, 0, 0);
                acc = __builtin_amdgcn_mfma_f32_16x16x32_bf16(alf[pi][0], b0, acc, 0, 0, 0);
                acc = __builtin_amdgcn_mfma_f32_16x16x32_bf16(alf[pi][1], b1, acc, 0, 0, 0);
                uint2 st;
                st.x = cvtpk(acc[0] + bo, acc[1] + bo);
                st.y = cvtpk(acc[2] + bo, acc[3] + bo);
                *reinterpret_cast<uint2*>(&cb[wo[pi]]) = st;
            }
        }
        __syncthreads();
        {
            int sel = ot >> 2;
            unsigned short* base =
                (sel == 0 ? qb : (sel == 1 ? kb : vb)) + (size_t)(b * 64 + (ot & 3) * 16) * PER_BO;
            union { unsigned short e[8]; uint4 v; } pk;
#pragma unroll
            for (int k = 0; k < 8; ++k) pk.e[k] = cb[so_lo + k * 16];
            *reinterpret_cast<uint4*>(base + so_po) = pk.v;
        }
    }
}

// ============================ Kernel 2: attention (direct-reg, d-planes) ============================
// Verbatim R12 structure (measured ~122us): zero-barrier pass1 with direct coalesced frag
// reads, wave-private pass2 (V LDS transpose, no barriers), paired 64B out stores.
__global__ __launch_bounds__(512, 4) void attn_kernel(
    const unsigned short* __restrict__ qb, const unsigned short* __restrict__ kb,
    const unsigned short* __restrict__ vb,
    const float* __restrict__ gamma, const float* __restrict__ beta,
    float* __restrict__ out)
{
    __shared__ char smem[61440];
    unsigned short* Vw = (unsigned short*)smem;            // per-wave [w:32][h: stride 36]
    unsigned short* Pb = (unsigned short*)(smem + 18432);
    float* Osf  = (float*)(smem + 27648);                  // 2 bufs x 8 planes x 528
    float* lred = (float*)(smem + 27648);
    float* rlb  = (float*)(smem + 27648 + 16896);

    int t = threadIdx.x;
    int l = t & 63;
    int dsub = t >> 6;
    int lr = l & 15, hk = l >> 4;

    // XCD pair swizzle (both halves of (b,oc) on same XCD, concurrent)
    int id = blockIdx.x;
    int xcd = id & 7;
    int k7 = id >> 3;
    int p = xcd + 8 * (k7 >> 1);
    int half = k7 & 1;
    int oc = p & 63;
    int b = p >> 6;
    int n = oc >> 4;

    const unsigned short* qp = qb + (size_t)(b * 64 + oc) * PER_BO;
    const unsigned short* kp = kb + (size_t)(b * 64 + oc) * PER_BO;
    const unsigned short* vp = vb + (size_t)(b * 64 + oc) * PER_BO;

    float gm = gamma[n], bt = beta[n];
    float decv[8];
#pragma unroll
    for (int gb = 0; gb < 2; ++gb)
#pragma unroll
        for (int r = 0; r < 4; ++r) {
            int hh = half * 16 + hk * 4 + r;
            int gg = gb * 16 + lr;
            float dc = 2.0f * fabsf((float)(hh - gg)) * gm + bt;
            float sp = fmaxf(dc, 0.0f) + log1pf(__expf(-fabsf(dc)));
            decv[gb * 4 + r] = __expf(-sp);
        }

    const float scale = 0.25f;
    f32x4 zero4 = {0.f, 0.f, 0.f, 0.f};

    unsigned int ep[48];
    float lacc[8] = {0.f, 0.f, 0.f, 0.f, 0.f, 0.f, 0.f, 0.f};

    // ---------------- PASS 1: direct-reg QK^T -> E + partial l (no LDS, no barriers) ----------------
    int qoff  = half * 512 + lr * 32 + hk * 8;
    int koff0 = lr * 32 + hk * 8;
    int koff1 = koff0 + 512;

    uint4 qv[2], k0v[2], k1v[2];
    {
        int b0p = dsub * 1024;
        qv[0]  = *reinterpret_cast<const uint4*>(qp + b0p + qoff);
        k0v[0] = *reinterpret_cast<const uint4*>(kp + b0p + koff0);
        k1v[0] = *reinterpret_cast<const uint4*>(kp + b0p + koff1);
        int b1p = (8 + dsub) * 1024;
        qv[1]  = *reinterpret_cast<const uint4*>(qp + b1p + qoff);
        k0v[1] = *reinterpret_cast<const uint4*>(kp + b1p + koff0);
        k1v[1] = *reinterpret_cast<const uint4*>(kp + b1p + koff1);
    }

#pragma unroll
    for (int ch = 0; ch < 12; ++ch) {
        int s = ch & 1;
        union { uint4 u; short8 v; } A, B0, B1;
        A.u = qv[s]; B0.u = k0v[s]; B1.u = k1v[s];
        f32x4 s0 = __builtin_amdgcn_mfma_f32_16x16x32_bf16(A.v, B0.v, zero4, 0, 0, 0);
        f32x4 s1 = __builtin_amdgcn_mfma_f32_16x16x32_bf16(A.v, B1.v, zero4, 0, 0, 0);
        if (ch < 10) {
            int bp = ((ch + 2) * 8 + dsub) * 1024;
            qv[s]  = *reinterpret_cast<const uint4*>(qp + bp + qoff);
            k0v[s] = *reinterpret_cast<const uint4*>(kp + bp + koff0);
            k1v[s] = *reinterpret_cast<const uint4*>(kp + bp + koff1);
        }
        float e[8];
#pragma unroll
        for (int r = 0; r < 4; ++r) {
            e[r]     = __expf(s0[r] * scale + decv[r]);
            e[4 + r] = __expf(s1[r] * scale + decv[4 + r]);
        }
#pragma unroll
        for (int i = 0; i < 8; ++i) lacc[i] += e[i];
        ep[ch * 4 + 0] = cvtpk(e[0], e[1]);
        ep[ch * 4 + 1] = cvtpk(e[2], e[3]);
        ep[ch * 4 + 2] = cvtpk(e[4], e[5]);
        ep[ch * 4 + 3] = cvtpk(e[6], e[7]);
    }

    // ---------------- l reduction (only cross-wave communication) ----------------
#pragma unroll
    for (int i = 0; i < 8; ++i)
        lred[dsub * 528 + (hk * 4 + (i & 3)) * 33 + (i >> 2) * 16 + lr] = lacc[i];
    __syncthreads();
    {
        float rsum = 0.f;
#pragma unroll
        for (int s = 0; s < 8; ++s) rsum += lred[s * 528 + (t >> 5) * 33 + (t & 31)];
        rlb[(t >> 5) * 33 + (t & 31)] = 1.0f / rsum;
    }
    __syncthreads();
    float rl8[8];
#pragma unroll
    for (int i = 0; i < 8; ++i)
        rl8[i] = rlb[(hk * 4 + (i & 3)) * 33 + (i >> 2) * 16 + lr];
    __syncthreads();

    // ---------------- PASS 2: wave-private V stage + P -> PV -> out ----------------
    int vgoff = l * 16;
    int vwbase = dsub * 1152 + ((l & 1) * 16) * 36 + (l >> 1);
    unsigned short* Pw = Pb + dsub * 576;

    uint4 vv0[2], vv1[2];
    {
        int b0p = dsub * 1024 + vgoff;
        vv0[0] = *reinterpret_cast<const uint4*>(vp + b0p);
        vv1[0] = *reinterpret_cast<const uint4*>(vp + b0p + 8);
        int b1p = (8 + dsub) * 1024 + vgoff;
        vv0[1] = *reinterpret_cast<const uint4*>(vp + b1p);
        vv1[1] = *reinterpret_cast<const uint4*>(vp + b1p + 8);
    }

    size_t obase0 = ((size_t)(b * 64 + oc) * 1024 + half * 512 + t) * 96;

#pragma unroll
    for (int ch = 0; ch < 12; ++ch) {
        int s = ch & 1;
        {
            union { uint4 u; unsigned short e[8]; } V0, V1;
            V0.u = vv0[s]; V1.u = vv1[s];
#pragma unroll
            for (int i = 0; i < 8; ++i) Vw[vwbase + i * 36] = V0.e[i];
#pragma unroll
            for (int i = 0; i < 8; ++i) Vw[vwbase + (i + 8) * 36] = V1.e[i];
        }
#pragma unroll
        for (int gb = 0; gb < 2; ++gb)
#pragma unroll
            for (int rp = 0; rp < 2; ++rp) {
                unsigned int u = ep[ch * 4 + gb * 2 + rp];
                float p0 = __uint_as_float(u << 16)         * rl8[gb * 4 + rp * 2];
                float p1 = __uint_as_float(u & 0xffff0000u) * rl8[gb * 4 + rp * 2 + 1];
                unsigned int pk = cvtpk(p0, p1);
                Pw[(hk * 4 + rp * 2) * 36 + gb * 16 + lr]     = (unsigned short)pk;
                Pw[(hk * 4 + rp * 2 + 1) * 36 + gb * 16 + lr] = (unsigned short)(pk >> 16);
            }
        if (ch < 10) {
            int bp = ((ch + 2) * 8 + dsub) * 1024 + vgoff;
            vv0[s] = *reinterpret_cast<const uint4*>(vp + bp);
            vv1[s] = *reinterpret_cast<const uint4*>(vp + bp + 8);
        }
        asm volatile("s_waitcnt lgkmcnt(0)" ::: "memory");
        __builtin_amdgcn_sched_barrier(0);
        short8 pa  = *reinterpret_cast<const short8*>(Pw + lr * 36 + hk * 8);
        short8 vb0 = *reinterpret_cast<const short8*>(Vw + dsub * 1152 + lr * 36 + hk * 8);
        short8 vb1 = *reinterpret_cast<const short8*>(Vw + dsub * 1152 + (16 + lr) * 36 + hk * 8);
        f32x4 o0 = __builtin_amdgcn_mfma_f32_16x16x32_bf16(pa, vb0, zero4, 0, 0, 0);
        f32x4 o1 = __builtin_amdgcn_mfma_f32_16x16x32_bf16(pa, vb1, zero4, 0, 0, 0);
        float* Od = Osf + s * 4224 + dsub * 528;
#pragma unroll
        for (int r = 0; r < 4; ++r) {
            Od[(hk * 4 + r) * 33 + lr]      = o0[r];
            Od[(hk * 4 + r) * 33 + 16 + lr] = o1[r];
        }
        if (ch & 1) {
            __syncthreads();
            int lidx = (t >> 5) * 33 + (t & 31);
            float4 q0, q1, q2, q3;
            q0.x = Osf[0 * 528 + lidx]; q0.y = Osf[1 * 528 + lidx];
            q0.z = Osf[2 * 528 + lidx]; q0.w = Osf[3 * 528 + lidx];
            q1.x = Osf[4 * 528 + lidx]; q1.y = Osf[5 * 528 + lidx];
            q1.z = Osf[6 * 528 + lidx]; q1.w = Osf[7 * 528 + lidx];
            q2.x = Osf[4224 + 0 * 528 + lidx]; q2.y = Osf[4224 + 1 * 528 + lidx];
            q2.z = Osf[4224 + 2 * 528 + lidx]; q2.w = Osf[4224 + 3 * 528 + lidx];
            q3.x = Osf[4224 + 4 * 528 + lidx]; q3.y = Osf[4224 + 5 * 528 + lidx];
            q3.z = Osf[4224 + 6 * 528 + lidx]; q3.w = Osf[4224 + 7 * 528 + lidx];
            float* po = out + obase0 + (ch >> 1) * 16;
            *reinterpret_cast<float4*>(po)      = q0;
            *reinterpret_cast<float4*>(po + 4)  = q1;
            *reinterpret_cast<float4*>(po + 8)  = q2;
            *reinterpret_cast<float4*>(po + 12) = q3;
            __syncthreads();
        }
    }
}

extern "C" void kernel_launch(void* const* d_in, const int* in_sizes, int n_in,
                              void* d_out, int out_size, void* d_ws, size_t ws_size,
                              hipStream_t stream) {
    const float* x     = (const float*)d_in[0];
    const float* w_sr  = (const float*)d_in[1];
    const float* b_sr  = (const float*)d_in[2];
    const float* Wq    = (const float*)d_in[3];
    const float* bq    = (const float*)d_in[4];
    const float* Wkv   = (const float*)d_in[5];
    const float* bkv   = (const float*)d_in[6];
    const float* gamma = (const float*)d_in[7];
    const float* beta  = (const float*)d_in[8];
    float* out = (float*)d_out;

    unsigned short* qb = (unsigned short*)d_ws;
    unsigned short* kb = qb + (size_t)50331648;
    unsigned short* vb = kb + (size_t)50331648;

    proj_mfma<<<1536, 1024, 0, stream>>>(x, w_sr, b_sr, Wq, bq, Wkv, bkv, qb, kb, vb);

    attn_kernel<<<1024, 512, 0, stream>>>(qb, kb, vb, gamma, beta, out);
}

// Round 16
// 286.989 us; speedup vs baseline: 1.3427x; 1.0186x over previous
//
#include <hip/hip_runtime.h>
#include <stdint.h>
#include <stddef.h>

typedef __attribute__((ext_vector_type(8))) short short8;
typedef __attribute__((ext_vector_type(4))) float f32x4;

// ---- sizes ----
// x: (8, 64, 32, 32, 96) f32.  NH=4, hd=16, scale = 0.25
// intermediates q,k,v: bf16, per (b,o): d-plane layout [d=0..95][pos=h*32+w] (2KB planes)
#define PER_BO 98304            // 96 d * 1024 pos ushorts per (b,o)

__device__ __forceinline__ unsigned int cvtpk(float lo, float hi) {
    unsigned int r;
    asm("v_cvt_pk_bf16_f32 %0, %1, %2" : "=v"(r) : "v"(lo), "v"(hi));
    return r;
}

// ============================ Kernel 1: projection GEMM (MFMA) ============================
// Block = (b, hrow, dg of 16): M = 32 w x 16 dd = 512. 1024 threads, 16 waves x 2 m-tiles.
// R15 + two fixes:
//  (1) Cb XOR-swizzle (dd ^ ((w>>2)&3)<<2): stream-out gather 4-way bank conflict -> 2-way
//      (free). Writes remain aligned uint2 (XOR touches only dd bits 2-3).
//  (2) barriers = lgkmcnt(0) + raw s_barrier (no vmcnt drain): stream-out stores stay in
//      flight across the 12 ot-barriers instead of waiting L2 ack each iteration.
__global__ __launch_bounds__(1024, 4) void proj_mfma(
    const float* __restrict__ x, const float* __restrict__ w_sr, const float* __restrict__ b_sr,
    const float* __restrict__ Wq, const float* __restrict__ bq,
    const float* __restrict__ Wkv, const float* __restrict__ bkv,
    unsigned short* __restrict__ qb, unsigned short* __restrict__ kb, unsigned short* __restrict__ vb)
{
    __shared__ unsigned short Wh[12288];
    __shared__ float bl[192];
    __shared__ unsigned short Cb[2 * 8256];   // [buf][o_l: stride 516][m: 512], m = w*16+dd (dd swizzled)

    int t = threadIdx.x;
    int bidx = blockIdx.x;
    int b = bidx & 7;                  // XCD = b
    int lf = bidx >> 3;                // 0..191
    int hrow = lf / 6;
    int dg = lf - hrow * 6;            // 0..5, d-group of 16

    int lane = t & 63;
    int wvi = t >> 6;                  // 0..15; wave owns w = wvi*2, wvi*2+1
    int lr = lane & 15, hk = lane >> 4;

    // ---- A: direct-to-reg; each wave-op = 4 aligned 64B lines ----
    const float* xb = x + (size_t)b * 6291456 + hrow * 3072 + dg * 16;
    float af[2][16];
#pragma unroll
    for (int pi = 0; pi < 2; ++pi) {
        int w = wvi * 2 + pi;
        const float* xp = xb + (size_t)(hk * 8) * 98304 + w * 96 + lr;
#pragma unroll
        for (int j = 0; j < 8; ++j) {
            af[pi][j]     = xp[(size_t)j * 98304];
            af[pi][8 + j] = xp[(size_t)(32 + j) * 98304];
        }
    }

    // ---- stage W_eff (bf16, swizzled) ----
#pragma unroll
    for (int i = 0; i < 3; ++i) {
        int qi = t + i * 1024;
        int o = qi >> 4;
        int cq = qi & 15;
        int c = cq * 4;
        float4 wv4;
        if (o < 64) wv4 = *reinterpret_cast<const float4*>(Wq + o * 64 + c);
        else {
            wv4 = *reinterpret_cast<const float4*>(Wkv + (o - 64) * 64 + c);
            float4 sr = *reinterpret_cast<const float4*>(w_sr + c);
            wv4.x *= sr.x; wv4.y *= sr.y; wv4.z *= sr.z; wv4.w *= sr.w;
        }
        uint2 pk; pk.x = cvtpk(wv4.x, wv4.y); pk.y = cvtpk(wv4.z, wv4.w);
        int sw = (cq >> 1) ^ (o & 7);
        *reinterpret_cast<uint2*>(&Wh[o * 64 + sw * 8 + (cq & 1) * 4]) = pk;
    }
    if (t < 192) {
        float s;
        if (t < 64) s = bq[t];
        else {
            s = bkv[t - 64];
            for (int c = 0; c < 64; ++c) s += Wkv[(t - 64) * 64 + c] * b_sr[c];
        }
        bl[t] = s;
    }
    __syncthreads();

    // ---- convert A to hi/lo bf16 fragments ----
    short8 ahf[2][2], alf[2][2];
#pragma unroll
    for (int pi = 0; pi < 2; ++pi) {
#pragma unroll
        for (int half = 0; half < 2; ++half) {
            union { unsigned int u[4]; short8 v; } H, L;
#pragma unroll
            for (int q = 0; q < 4; ++q) {
                float f0 = af[pi][half * 8 + 2 * q];
                float f1 = af[pi][half * 8 + 2 * q + 1];
                unsigned int hp = cvtpk(f0, f1);
                float h0 = __uint_as_float(hp << 16);
                float h1 = __uint_as_float(hp & 0xffff0000u);
                H.u[q] = hp;
                L.u[q] = cvtpk(f0 - h0, f1 - h1);
            }
            ahf[pi][half] = H.v; alf[pi][half] = L.v;
        }
    }

    // ---- Cb write offsets (swizzled): rows dd0..dd0+3 stay consecutive after XOR ----
    int wo[2];
#pragma unroll
    for (int pi = 0; pi < 2; ++pi) {
        int w = wvi * 2 + pi;
        wo[pi] = lr * 516 + w * 16 + ((hk * 4) ^ (((w >> 2) & 3) << 2));
    }

    // ---- stream-out decode: 1 unit/thread = 8 w at fixed (o_l, dd) = 16B ----
    int o_l = t >> 6;
    int dd  = (t >> 2) & 15;
    int w8  = t & 3;
    size_t so_po = (size_t)o_l * PER_BO + (size_t)(dg * 16 + dd) * 1024 + hrow * 32 + w8 * 8;
    int so_base = o_l * 516 + w8 * 128;   // + k*16 + (dd ^ swz(w8,k))

    float biasv[12];
#pragma unroll
    for (int ot = 0; ot < 12; ++ot) biasv[ot] = bl[ot * 16 + lr];

    f32x4 zero4 = {0.f, 0.f, 0.f, 0.f};
    int s7 = lr & 7;

#pragma unroll
    for (int ot = 0; ot < 12; ++ot) {
        unsigned short* cb = Cb + (ot & 1) * 8256;
        {
            int o = ot * 16 + lr;
            const unsigned short* wr = &Wh[o * 64];
            short8 b0 = *reinterpret_cast<const short8*>(wr + ((hk ^ s7) * 8));
            short8 b1 = *reinterpret_cast<const short8*>(wr + (((hk + 4) ^ s7) * 8));
            float bo = biasv[ot];
#pragma unroll
            for (int pi = 0; pi < 2; ++pi) {
                f32x4 acc = __builtin_amdgcn_mfma_f32_16x16x32_bf16(ahf[pi][0], b0, zero4, 0, 0, 0);
                acc = __builtin_amdgcn_mfma_f32_16x16x32_bf16(ahf[pi][1], b1, acc, 0, 0, 0);
                acc = __builtin_amdgcn_mfma_f32_16x16x32_bf16(alf[pi][0], b0, acc, 0, 0, 0);
                acc = __builtin_amdgcn_mfma_f32_16x16x32_bf16(alf[pi][1], b1, acc, 0, 0, 0);
                uint2 st;
                st.x = cvtpk(acc[0] + bo, acc[1] + bo);
                st.y = cvtpk(acc[2] + bo, acc[3] + bo);
                *reinterpret_cast<uint2*>(&cb[wo[pi]]) = st;
            }
        }
        // barrier WITHOUT vmcnt drain: only LDS ordering needed (stores fly across)
        asm volatile("s_waitcnt lgkmcnt(0)" ::: "memory");
        __builtin_amdgcn_s_barrier();
        {
            int sel = ot >> 2;
            unsigned short* base =
                (sel == 0 ? qb : (sel == 1 ? kb : vb)) + (size_t)(b * 64 + (ot & 3) * 16) * PER_BO;
            union { unsigned short e[8]; uint4 v; } pk;
#pragma unroll
            for (int k = 0; k < 8; ++k)
                pk.e[k] = cb[so_base + k * 16 + (dd ^ ((((w8 << 1) + (k >> 2)) & 3) << 2))];
            *reinterpret_cast<uint4*>(base + so_po) = pk.v;
        }
    }
}

// ============================ Kernel 2: attention (direct-reg, d-planes) ============================
// Verbatim R12/R15 structure (measured ~122-127us): zero-barrier pass1 with direct coalesced
// frag reads, wave-private pass2 (V LDS transpose, no barriers), paired 64B out stores.
__global__ __launch_bounds__(512, 4) void attn_kernel(
    const unsigned short* __restrict__ qb, const unsigned short* __restrict__ kb,
    const unsigned short* __restrict__ vb,
    const float* __restrict__ gamma, const float* __restrict__ beta,
    float* __restrict__ out)
{
    __shared__ char smem[61440];
    unsigned short* Vw = (unsigned short*)smem;            // per-wave [w:32][h: stride 36]
    unsigned short* Pb = (unsigned short*)(smem + 18432);
    float* Osf  = (float*)(smem + 27648);                  // 2 bufs x 8 planes x 528
    float* lred = (float*)(smem + 27648);
    float* rlb  = (float*)(smem + 27648 + 16896);

    int t = threadIdx.x;
    int l = t & 63;
    int dsub = t >> 6;
    int lr = l & 15, hk = l >> 4;

    // XCD pair swizzle (both halves of (b,oc) on same XCD, concurrent)
    int id = blockIdx.x;
    int xcd = id & 7;
    int k7 = id >> 3;
    int p = xcd + 8 * (k7 >> 1);
    int half = k7 & 1;
    int oc = p & 63;
    int b = p >> 6;
    int n = oc >> 4;

    const unsigned short* qp = qb + (size_t)(b * 64 + oc) * PER_BO;
    const unsigned short* kp = kb + (size_t)(b * 64 + oc) * PER_BO;
    const unsigned short* vp = vb + (size_t)(b * 64 + oc) * PER_BO;

    float gm = gamma[n], bt = beta[n];
    float decv[8];
#pragma unroll
    for (int gb = 0; gb < 2; ++gb)
#pragma unroll
        for (int r = 0; r < 4; ++r) {
            int hh = half * 16 + hk * 4 + r;
            int gg = gb * 16 + lr;
            float dc = 2.0f * fabsf((float)(hh - gg)) * gm + bt;
            float sp = fmaxf(dc, 0.0f) + log1pf(__expf(-fabsf(dc)));
            decv[gb * 4 + r] = __expf(-sp);
        }

    const float scale = 0.25f;
    f32x4 zero4 = {0.f, 0.f, 0.f, 0.f};

    unsigned int ep[48];
    float lacc[8] = {0.f, 0.f, 0.f, 0.f, 0.f, 0.f, 0.f, 0.f};

    // ---------------- PASS 1: direct-reg QK^T -> E + partial l (no LDS, no barriers) ----------------
    int qoff  = half * 512 + lr * 32 + hk * 8;
    int koff0 = lr * 32 + hk * 8;
    int koff1 = koff0 + 512;

    uint4 qv[2], k0v[2], k1v[2];
    {
        int b0p = dsub * 1024;
        qv[0]  = *reinterpret_cast<const uint4*>(qp + b0p + qoff);
        k0v[0] = *reinterpret_cast<const uint4*>(kp + b0p + koff0);
        k1v[0] = *reinterpret_cast<const uint4*>(kp + b0p + koff1);
        int b1p = (8 + dsub) * 1024;
        qv[1]  = *reinterpret_cast<const uint4*>(qp + b1p + qoff);
        k0v[1] = *reinterpret_cast<const uint4*>(kp + b1p + koff0);
        k1v[1] = *reinterpret_cast<const uint4*>(kp + b1p + koff1);
    }

#pragma unroll
    for (int ch = 0; ch < 12; ++ch) {
        int s = ch & 1;
        union { uint4 u; short8 v; } A, B0, B1;
        A.u = qv[s]; B0.u = k0v[s]; B1.u = k1v[s];
        f32x4 s0 = __builtin_amdgcn_mfma_f32_16x16x32_bf16(A.v, B0.v, zero4, 0, 0, 0);
        f32x4 s1 = __builtin_amdgcn_mfma_f32_16x16x32_bf16(A.v, B1.v, zero4, 0, 0, 0);
        if (ch < 10) {
            int bp = ((ch + 2) * 8 + dsub) * 1024;
            qv[s]  = *reinterpret_cast<const uint4*>(qp + bp + qoff);
            k0v[s] = *reinterpret_cast<const uint4*>(kp + bp + koff0);
            k1v[s] = *reinterpret_cast<const uint4*>(kp + bp + koff1);
        }
        float e[8];
#pragma unroll
        for (int r = 0; r < 4; ++r) {
            e[r]     = __expf(s0[r] * scale + decv[r]);
            e[4 + r] = __expf(s1[r] * scale + decv[4 + r]);
        }
#pragma unroll
        for (int i = 0; i < 8; ++i) lacc[i] += e[i];
        ep[ch * 4 + 0] = cvtpk(e[0], e[1]);
        ep[ch * 4 + 1] = cvtpk(e[2], e[3]);
        ep[ch * 4 + 2] = cvtpk(e[4], e[5]);
        ep[ch * 4 + 3] = cvtpk(e[6], e[7]);
    }

    // ---------------- l reduction (only cross-wave communication) ----------------
#pragma unroll
    for (int i = 0; i < 8; ++i)
        lred[dsub * 528 + (hk * 4 + (i & 3)) * 33 + (i >> 2) * 16 + lr] = lacc[i];
    __syncthreads();
    {
        float rsum = 0.f;
#pragma unroll
        for (int s = 0; s < 8; ++s) rsum += lred[s * 528 + (t >> 5) * 33 + (t & 31)];
        rlb[(t >> 5) * 33 + (t & 31)] = 1.0f / rsum;
    }
    __syncthreads();
    float rl8[8];
#pragma unroll
    for (int i = 0; i < 8; ++i)
        rl8[i] = rlb[(hk * 4 + (i & 3)) * 33 + (i >> 2) * 16 + lr];
    __syncthreads();

    // ---------------- PASS 2: wave-private V stage + P -> PV -> out ----------------
    int vgoff = l * 16;
    int vwbase = dsub * 1152 + ((l & 1) * 16) * 36 + (l >> 1);
    unsigned short* Pw = Pb + dsub * 576;

    uint4 vv0[2], vv1[2];
    {
        int b0p = dsub * 1024 + vgoff;
        vv0[0] = *reinterpret_cast<const uint4*>(vp + b0p);
        vv1[0] = *reinterpret_cast<const uint4*>(vp + b0p + 8);
        int b1p = (8 + dsub) * 1024 + vgoff;
        vv0[1] = *reinterpret_cast<const uint4*>(vp + b1p);
        vv1[1] = *reinterpret_cast<const uint4*>(vp + b1p + 8);
    }

    size_t obase0 = ((size_t)(b * 64 + oc) * 1024 + half * 512 + t) * 96;

#pragma unroll
    for (int ch = 0; ch < 12; ++ch) {
        int s = ch & 1;
        {
            union { uint4 u; unsigned short e[8]; } V0, V1;
            V0.u = vv0[s]; V1.u = vv1[s];
#pragma unroll
            for (int i = 0; i < 8; ++i) Vw[vwbase + i * 36] = V0.e[i];
#pragma unroll
            for (int i = 0; i < 8; ++i) Vw[vwbase + (i + 8) * 36] = V1.e[i];
        }
#pragma unroll
        for (int gb = 0; gb < 2; ++gb)
#pragma unroll
            for (int rp = 0; rp < 2; ++rp) {
                unsigned int u = ep[ch * 4 + gb * 2 + rp];
                float p0 = __uint_as_float(u << 16)         * rl8[gb * 4 + rp * 2];
                float p1 = __uint_as_float(u & 0xffff0000u) * rl8[gb * 4 + rp * 2 + 1];
                unsigned int pk = cvtpk(p0, p1);
                Pw[(hk * 4 + rp * 2) * 36 + gb * 16 + lr]     = (unsigned short)pk;
                Pw[(hk * 4 + rp * 2 + 1) * 36 + gb * 16 + lr] = (unsigned short)(pk >> 16);
            }
        if (ch < 10) {
            int bp = ((ch + 2) * 8 + dsub) * 1024 + vgoff;
            vv0[s] = *reinterpret_cast<const uint4*>(vp + bp);
            vv1[s] = *reinterpret_cast<const uint4*>(vp + bp + 8);
        }
        asm volatile("s_waitcnt lgkmcnt(0)" ::: "memory");
        __builtin_amdgcn_sched_barrier(0);
        short8 pa  = *reinterpret_cast<const short8*>(Pw + lr * 36 + hk * 8);
        short8 vb0 = *reinterpret_cast<const short8*>(Vw + dsub * 1152 + lr * 36 + hk * 8);
        short8 vb1 = *reinterpret_cast<const short8*>(Vw + dsub * 1152 + (16 + lr) * 36 + hk * 8);
        f32x4 o0 = __builtin_amdgcn_mfma_f32_16x16x32_bf16(pa, vb0, zero4, 0, 0, 0);
        f32x4 o1 = __builtin_amdgcn_mfma_f32_16x16x32_bf16(pa, vb1, zero4, 0, 0, 0);
        float* Od = Osf + s * 4224 + dsub * 528;
#pragma unroll
        for (int r = 0; r < 4; ++r) {
            Od[(hk * 4 + r) * 33 + lr]      = o0[r];
            Od[(hk * 4 + r) * 33 + 16 + lr] = o1[r];
        }
        if (ch & 1) {
            __syncthreads();
            int lidx = (t >> 5) * 33 + (t & 31);
            float4 q0, q1, q2, q3;
            q0.x = Osf[0 * 528 + lidx]; q0.y = Osf[1 * 528 + lidx];
            q0.z = Osf[2 * 528 + lidx]; q0.w = Osf[3 * 528 + lidx];
            q1.x = Osf[4 * 528 + lidx]; q1.y = Osf[5 * 528 + lidx];
            q1.z = Osf[6 * 528 + lidx]; q1.w = Osf[7 * 528 + lidx];
            q2.x = Osf[4224 + 0 * 528 + lidx]; q2.y = Osf[4224 + 1 * 528 + lidx];
            q2.z = Osf[4224 + 2 * 528 + lidx]; q2.w = Osf[4224 + 3 * 528 + lidx];
            q3.x = Osf[4224 + 4 * 528 + lidx]; q3.y = Osf[4224 + 5 * 528 + lidx];
            q3.z = Osf[4224 + 6 * 528 + lidx]; q3.w = Osf[4224 + 7 * 528 + lidx];
            float* po = out + obase0 + (ch >> 1) * 16;
            *reinterpret_cast<float4*>(po)      = q0;
            *reinterpret_cast<float4*>(po + 4)  = q1;
            *reinterpret_cast<float4*>(po + 8)  = q2;
            *reinterpret_cast<float4*>(po + 12) = q3;
            __syncthreads();
        }
    }
}

extern "C" void kernel_launch(void* const* d_in, const int* in_sizes, int n_in,
                              void* d_out, int out_size, void* d_ws, size_t ws_size,
                              hipStream_t stream) {
    const float* x     = (const float*)d_in[0];
    const float* w_sr  = (const float*)d_in[1];
    const float* b_sr  = (const float*)d_in[2];
    const float* Wq    = (const float*)d_in[3];
    const float* bq    = (const float*)d_in[4];
    const float* Wkv   = (const float*)d_in[5];
    const float* bkv   = (const float*)d_in[6];
    const float* gamma = (const float*)d_in[7];
    const float* beta  = (const float*)d_in[8];
    float* out = (float*)d_out;

    unsigned short* qb = (unsigned short*)d_ws;
    unsigned short* kb = qb + (size_t)50331648;
    unsigned short* vb = kb + (size_t)50331648;

    proj_mfma<<<1536, 1024, 0, stream>>>(x, w_sr, b_sr, Wq, bq, Wkv, bkv, qb, kb, vb);

    attn_kernel<<<1024, 512, 0, stream>>>(qb, kb, vb, gamma, beta, out);
}

// Round 17
// 284.402 us; speedup vs baseline: 1.3549x; 1.0091x over previous
//
#include <hip/hip_runtime.h>
#include <stdint.h>
#include <stddef.h>

typedef __attribute__((ext_vector_type(8))) short short8;
typedef __attribute__((ext_vector_type(4))) float f32x4;

// ---- sizes ----
// x: (8, 64, 32, 32, 96) f32.  NH=4, hd=16, scale = 0.25
// intermediates q,k,v: bf16, per (b,o): d-plane layout [d=0..95][pos=h*32+w] (2KB planes)
#define PER_BO 98304            // 96 d * 1024 pos ushorts per (b,o)

__device__ __forceinline__ unsigned int cvtpk(float lo, float hi) {
    unsigned int r;
    asm("v_cvt_pk_bf16_f32 %0, %1, %2" : "=v"(r) : "v"(lo), "v"(hi));
    return r;
}

// ============================ Kernel 1: projection GEMM (MFMA) ============================
// (verbatim R16: aligned A-loads, XOR-swizzled Cb, lgkm-only barriers)
__global__ __launch_bounds__(1024, 4) void proj_mfma(
    const float* __restrict__ x, const float* __restrict__ w_sr, const float* __restrict__ b_sr,
    const float* __restrict__ Wq, const float* __restrict__ bq,
    const float* __restrict__ Wkv, const float* __restrict__ bkv,
    unsigned short* __restrict__ qb, unsigned short* __restrict__ kb, unsigned short* __restrict__ vb)
{
    __shared__ unsigned short Wh[12288];
    __shared__ float bl[192];
    __shared__ unsigned short Cb[2 * 8256];   // [buf][o_l: stride 516][m: 512], dd swizzled

    int t = threadIdx.x;
    int bidx = blockIdx.x;
    int b = bidx & 7;                  // XCD = b
    int lf = bidx >> 3;                // 0..191
    int hrow = lf / 6;
    int dg = lf - hrow * 6;            // 0..5, d-group of 16

    int lane = t & 63;
    int wvi = t >> 6;                  // 0..15; wave owns w = wvi*2, wvi*2+1
    int lr = lane & 15, hk = lane >> 4;

    const float* xb = x + (size_t)b * 6291456 + hrow * 3072 + dg * 16;
    float af[2][16];
#pragma unroll
    for (int pi = 0; pi < 2; ++pi) {
        int w = wvi * 2 + pi;
        const float* xp = xb + (size_t)(hk * 8) * 98304 + w * 96 + lr;
#pragma unroll
        for (int j = 0; j < 8; ++j) {
            af[pi][j]     = xp[(size_t)j * 98304];
            af[pi][8 + j] = xp[(size_t)(32 + j) * 98304];
        }
    }

#pragma unroll
    for (int i = 0; i < 3; ++i) {
        int qi = t + i * 1024;
        int o = qi >> 4;
        int cq = qi & 15;
        int c = cq * 4;
        float4 wv4;
        if (o < 64) wv4 = *reinterpret_cast<const float4*>(Wq + o * 64 + c);
        else {
            wv4 = *reinterpret_cast<const float4*>(Wkv + (o - 64) * 64 + c);
            float4 sr = *reinterpret_cast<const float4*>(w_sr + c);
            wv4.x *= sr.x; wv4.y *= sr.y; wv4.z *= sr.z; wv4.w *= sr.w;
        }
        uint2 pk; pk.x = cvtpk(wv4.x, wv4.y); pk.y = cvtpk(wv4.z, wv4.w);
        int sw = (cq >> 1) ^ (o & 7);
        *reinterpret_cast<uint2*>(&Wh[o * 64 + sw * 8 + (cq & 1) * 4]) = pk;
    }
    if (t < 192) {
        float s;
        if (t < 64) s = bq[t];
        else {
            s = bkv[t - 64];
            for (int c = 0; c < 64; ++c) s += Wkv[(t - 64) * 64 + c] * b_sr[c];
        }
        bl[t] = s;
    }
    __syncthreads();

    short8 ahf[2][2], alf[2][2];
#pragma unroll
    for (int pi = 0; pi < 2; ++pi) {
#pragma unroll
        for (int half = 0; half < 2; ++half) {
            union { unsigned int u[4]; short8 v; } H, L;
#pragma unroll
            for (int q = 0; q < 4; ++q) {
                float f0 = af[pi][half * 8 + 2 * q];
                float f1 = af[pi][half * 8 + 2 * q + 1];
                unsigned int hp = cvtpk(f0, f1);
                float h0 = __uint_as_float(hp << 16);
                float h1 = __uint_as_float(hp & 0xffff0000u);
                H.u[q] = hp;
                L.u[q] = cvtpk(f0 - h0, f1 - h1);
            }
            ahf[pi][half] = H.v; alf[pi][half] = L.v;
        }
    }

    int wo[2];
#pragma unroll
    for (int pi = 0; pi < 2; ++pi) {
        int w = wvi * 2 + pi;
        wo[pi] = lr * 516 + w * 16 + ((hk * 4) ^ (((w >> 2) & 3) << 2));
    }

    int o_l = t >> 6;
    int dd  = (t >> 2) & 15;
    int w8  = t & 3;
    size_t so_po = (size_t)o_l * PER_BO + (size_t)(dg * 16 + dd) * 1024 + hrow * 32 + w8 * 8;
    int so_base = o_l * 516 + w8 * 128;

    float biasv[12];
#pragma unroll
    for (int ot = 0; ot < 12; ++ot) biasv[ot] = bl[ot * 16 + lr];

    f32x4 zero4 = {0.f, 0.f, 0.f, 0.f};
    int s7 = lr & 7;

#pragma unroll
    for (int ot = 0; ot < 12; ++ot) {
        unsigned short* cb = Cb + (ot & 1) * 8256;
        {
            int o = ot * 16 + lr;
            const unsigned short* wr = &Wh[o * 64];
            short8 b0 = *reinterpret_cast<const short8*>(wr + ((hk ^ s7) * 8));
            short8 b1 = *reinterpret_cast<const short8*>(wr + (((hk + 4) ^ s7) * 8));
            float bo = biasv[ot];
#pragma unroll
            for (int pi = 0; pi < 2; ++pi) {
                f32x4 acc = __builtin_amdgcn_mfma_f32_16x16x32_bf16(ahf[pi][0], b0, zero4, 0, 0, 0);
                acc = __builtin_amdgcn_mfma_f32_16x16x32_bf16(ahf[pi][1], b1, acc, 0, 0, 0);
                acc = __builtin_amdgcn_mfma_f32_16x16x32_bf16(alf[pi][0], b0, acc, 0, 0, 0);
                acc = __builtin_amdgcn_mfma_f32_16x16x32_bf16(alf[pi][1], b1, acc, 0, 0, 0);
                uint2 st;
                st.x = cvtpk(acc[0] + bo, acc[1] + bo);
                st.y = cvtpk(acc[2] + bo, acc[3] + bo);
                *reinterpret_cast<uint2*>(&cb[wo[pi]]) = st;
            }
        }
        asm volatile("s_waitcnt lgkmcnt(0)" ::: "memory");
        __builtin_amdgcn_s_barrier();
        {
            int sel = ot >> 2;
            unsigned short* base =
                (sel == 0 ? qb : (sel == 1 ? kb : vb)) + (size_t)(b * 64 + (ot & 3) * 16) * PER_BO;
            union { unsigned short e[8]; uint4 v; } pk;
#pragma unroll
            for (int k = 0; k < 8; ++k)
                pk.e[k] = cb[so_base + k * 16 + (dd ^ ((((w8 << 1) + (k >> 2)) & 3) << 2))];
            *reinterpret_cast<uint4*>(base + so_po) = pk.v;
        }
    }
}

// ============================ Kernel 2: attention (direct-reg, d-planes, Pb aliased) ============================
// R12/R16 structure, but Pb eliminated: each wave's P-staging area aliases the first 288
// floats of its own Osf[s] plane (P consumed by the pa-read BEFORE the plane's O-write;
// pair-flush moved to the START of the next even ch, barrier-protected both sides).
// LDS 61440 -> 52224 => 3 blocks/CU (24 waves) instead of 2.
__global__ __launch_bounds__(512, 4) void attn_kernel(
    const unsigned short* __restrict__ qb, const unsigned short* __restrict__ kb,
    const unsigned short* __restrict__ vb,
    const float* __restrict__ gamma, const float* __restrict__ beta,
    float* __restrict__ out)
{
    __shared__ char smem[52224];
    unsigned short* Vw = (unsigned short*)smem;            // per-wave [w:32][h: stride 36], 18432 B
    float* Osf  = (float*)(smem + 18432);                  // 2 bufs x 8 planes x 528 = 33792 B
    float* lred = (float*)(smem + 18432);                  // aliases Osf (pass1 only)
    float* rlb  = (float*)(smem + 18432 + 16896);

    int t = threadIdx.x;
    int l = t & 63;
    int dsub = t >> 6;
    int lr = l & 15, hk = l >> 4;

    // XCD pair swizzle (both halves of (b,oc) on same XCD, concurrent)
    int id = blockIdx.x;
    int xcd = id & 7;
    int k7 = id >> 3;
    int p = xcd + 8 * (k7 >> 1);
    int half = k7 & 1;
    int oc = p & 63;
    int b = p >> 6;
    int n = oc >> 4;

    const unsigned short* qp = qb + (size_t)(b * 64 + oc) * PER_BO;
    const unsigned short* kp = kb + (size_t)(b * 64 + oc) * PER_BO;
    const unsigned short* vp = vb + (size_t)(b * 64 + oc) * PER_BO;

    float gm = gamma[n], bt = beta[n];
    float decv[8];
#pragma unroll
    for (int gb = 0; gb < 2; ++gb)
#pragma unroll
        for (int r = 0; r < 4; ++r) {
            int hh = half * 16 + hk * 4 + r;
            int gg = gb * 16 + lr;
            float dc = 2.0f * fabsf((float)(hh - gg)) * gm + bt;
            float sp = fmaxf(dc, 0.0f) + log1pf(__expf(-fabsf(dc)));
            decv[gb * 4 + r] = __expf(-sp);
        }

    const float scale = 0.25f;
    f32x4 zero4 = {0.f, 0.f, 0.f, 0.f};

    unsigned int ep[48];
    float lacc[8] = {0.f, 0.f, 0.f, 0.f, 0.f, 0.f, 0.f, 0.f};

    // ---------------- PASS 1: direct-reg QK^T -> E + partial l (no LDS, no barriers) ----------------
    int qoff  = half * 512 + lr * 32 + hk * 8;
    int koff0 = lr * 32 + hk * 8;
    int koff1 = koff0 + 512;

    uint4 qv[2], k0v[2], k1v[2];
    {
        int b0p = dsub * 1024;
        qv[0]  = *reinterpret_cast<const uint4*>(qp + b0p + qoff);
        k0v[0] = *reinterpret_cast<const uint4*>(kp + b0p + koff0);
        k1v[0] = *reinterpret_cast<const uint4*>(kp + b0p + koff1);
        int b1p = (8 + dsub) * 1024;
        qv[1]  = *reinterpret_cast<const uint4*>(qp + b1p + qoff);
        k0v[1] = *reinterpret_cast<const uint4*>(kp + b1p + koff0);
        k1v[1] = *reinterpret_cast<const uint4*>(kp + b1p + koff1);
    }

#pragma unroll
    for (int ch = 0; ch < 12; ++ch) {
        int s = ch & 1;
        union { uint4 u; short8 v; } A, B0, B1;
        A.u = qv[s]; B0.u = k0v[s]; B1.u = k1v[s];
        f32x4 s0 = __builtin_amdgcn_mfma_f32_16x16x32_bf16(A.v, B0.v, zero4, 0, 0, 0);
        f32x4 s1 = __builtin_amdgcn_mfma_f32_16x16x32_bf16(A.v, B1.v, zero4, 0, 0, 0);
        if (ch < 10) {
            int bp = ((ch + 2) * 8 + dsub) * 1024;
            qv[s]  = *reinterpret_cast<const uint4*>(qp + bp + qoff);
            k0v[s] = *reinterpret_cast<const uint4*>(kp + bp + koff0);
            k1v[s] = *reinterpret_cast<const uint4*>(kp + bp + koff1);
        }
        float e[8];
#pragma unroll
        for (int r = 0; r < 4; ++r) {
            e[r]     = __expf(s0[r] * scale + decv[r]);
            e[4 + r] = __expf(s1[r] * scale + decv[4 + r]);
        }
#pragma unroll
        for (int i = 0; i < 8; ++i) lacc[i] += e[i];
        ep[ch * 4 + 0] = cvtpk(e[0], e[1]);
        ep[ch * 4 + 1] = cvtpk(e[2], e[3]);
        ep[ch * 4 + 2] = cvtpk(e[4], e[5]);
        ep[ch * 4 + 3] = cvtpk(e[6], e[7]);
    }

    // ---------------- l reduction (only cross-wave communication) ----------------
#pragma unroll
    for (int i = 0; i < 8; ++i)
        lred[dsub * 528 + (hk * 4 + (i & 3)) * 33 + (i >> 2) * 16 + lr] = lacc[i];
    __syncthreads();
    {
        float rsum = 0.f;
#pragma unroll
        for (int s = 0; s < 8; ++s) rsum += lred[s * 528 + (t >> 5) * 33 + (t & 31)];
        rlb[(t >> 5) * 33 + (t & 31)] = 1.0f / rsum;
    }
    __syncthreads();
    float rl8[8];
#pragma unroll
    for (int i = 0; i < 8; ++i)
        rl8[i] = rlb[(hk * 4 + (i & 3)) * 33 + (i >> 2) * 16 + lr];
    __syncthreads();

    // ---------------- PASS 2: wave-private V stage + P (aliased in Osf) -> PV -> out ----------------
    int vgoff = l * 16;
    int vwbase = dsub * 1152 + ((l & 1) * 16) * 36 + (l >> 1);

    uint4 vv0[2], vv1[2];
    {
        int b0p = dsub * 1024 + vgoff;
        vv0[0] = *reinterpret_cast<const uint4*>(vp + b0p);
        vv1[0] = *reinterpret_cast<const uint4*>(vp + b0p + 8);
        int b1p = (8 + dsub) * 1024 + vgoff;
        vv0[1] = *reinterpret_cast<const uint4*>(vp + b1p);
        vv1[1] = *reinterpret_cast<const uint4*>(vp + b1p + 8);
    }

    size_t obase0 = ((size_t)(b * 64 + oc) * 1024 + half * 512 + t) * 96;
    int lidx = (t >> 5) * 33 + (t & 31);

#pragma unroll
    for (int ch = 0; ch < 12; ++ch) {
        int s = ch & 1;
        // flush previous ch-pair at the start of each even ch (both Osf bufs complete)
        if (s == 0 && ch >= 2) {
            __syncthreads();
            float4 q0, q1, q2, q3;
            q0.x = Osf[0 * 528 + lidx]; q0.y = Osf[1 * 528 + lidx];
            q0.z = Osf[2 * 528 + lidx]; q0.w = Osf[3 * 528 + lidx];
            q1.x = Osf[4 * 528 + lidx]; q1.y = Osf[5 * 528 + lidx];
            q1.z = Osf[6 * 528 + lidx]; q1.w = Osf[7 * 528 + lidx];
            q2.x = Osf[4224 + 0 * 528 + lidx]; q2.y = Osf[4224 + 1 * 528 + lidx];
            q2.z = Osf[4224 + 2 * 528 + lidx]; q2.w = Osf[4224 + 3 * 528 + lidx];
            q3.x = Osf[4224 + 4 * 528 + lidx]; q3.y = Osf[4224 + 5 * 528 + lidx];
            q3.z = Osf[4224 + 6 * 528 + lidx]; q3.w = Osf[4224 + 7 * 528 + lidx];
            float* po = out + obase0 + ((ch >> 1) - 1) * 16;
            *reinterpret_cast<float4*>(po)      = q0;
            *reinterpret_cast<float4*>(po + 4)  = q1;
            *reinterpret_cast<float4*>(po + 8)  = q2;
            *reinterpret_cast<float4*>(po + 12) = q3;
            __syncthreads();
        }
        // stage V-plane transposed into wave-private Vw
        {
            union { uint4 u; unsigned short e[8]; } V0, V1;
            V0.u = vv0[s]; V1.u = vv1[s];
#pragma unroll
            for (int i = 0; i < 8; ++i) Vw[vwbase + i * 36] = V0.e[i];
#pragma unroll
            for (int i = 0; i < 8; ++i) Vw[vwbase + (i + 8) * 36] = V1.e[i];
        }
        // build P into the wave's own Osf[s] plane head (consumed before the O-write)
        unsigned short* Pw = (unsigned short*)(Osf + s * 4224 + dsub * 528);
#pragma unroll
        for (int gb = 0; gb < 2; ++gb)
#pragma unroll
            for (int rp = 0; rp < 2; ++rp) {
                unsigned int u = ep[ch * 4 + gb * 2 + rp];
                float p0 = __uint_as_float(u << 16)         * rl8[gb * 4 + rp * 2];
                float p1 = __uint_as_float(u & 0xffff0000u) * rl8[gb * 4 + rp * 2 + 1];
                unsigned int pk = cvtpk(p0, p1);
                Pw[(hk * 4 + rp * 2) * 36 + gb * 16 + lr]     = (unsigned short)pk;
                Pw[(hk * 4 + rp * 2 + 1) * 36 + gb * 16 + lr] = (unsigned short)(pk >> 16);
            }
        if (ch < 10) {
            int bp = ((ch + 2) * 8 + dsub) * 1024 + vgoff;
            vv0[s] = *reinterpret_cast<const uint4*>(vp + bp);
            vv1[s] = *reinterpret_cast<const uint4*>(vp + bp + 8);
        }
        asm volatile("s_waitcnt lgkmcnt(0)" ::: "memory");
        __builtin_amdgcn_sched_barrier(0);
        short8 pa  = *reinterpret_cast<const short8*>(Pw + lr * 36 + hk * 8);
        short8 vb0 = *reinterpret_cast<const short8*>(Vw + dsub * 1152 + lr * 36 + hk * 8);
        short8 vb1 = *reinterpret_cast<const short8*>(Vw + dsub * 1152 + (16 + lr) * 36 + hk * 8);
        f32x4 o0 = __builtin_amdgcn_mfma_f32_16x16x32_bf16(pa, vb0, zero4, 0, 0, 0);
        f32x4 o1 = __builtin_amdgcn_mfma_f32_16x16x32_bf16(pa, vb1, zero4, 0, 0, 0);
        float* Od = Osf + s * 4224 + dsub * 528;
#pragma unroll
        for (int r = 0; r < 4; ++r) {
            Od[(hk * 4 + r) * 33 + lr]      = o0[r];
            Od[(hk * 4 + r) * 33 + 16 + lr] = o1[r];
        }
    }
    // final pair flush
    {
        __syncthreads();
        float4 q0, q1, q2, q3;
        q0.x = Osf[0 * 528 + lidx]; q0.y = Osf[1 * 528 + lidx];
        q0.z = Osf[2 * 528 + lidx]; q0.w = Osf[3 * 528 + lidx];
        q1.x = Osf[4 * 528 + lidx]; q1.y = Osf[5 * 528 + lidx];
        q1.z = Osf[6 * 528 + lidx]; q1.w = Osf[7 * 528 + lidx];
        q2.x = Osf[4224 + 0 * 528 + lidx]; q2.y = Osf[4224 + 1 * 528 + lidx];
        q2.z = Osf[4224 + 2 * 528 + lidx]; q2.w = Osf[4224 + 3 * 528 + lidx];
        q3.x = Osf[4224 + 4 * 528 + lidx]; q3.y = Osf[4224 + 5 * 528 + lidx];
        q3.z = Osf[4224 + 6 * 528 + lidx]; q3.w = Osf[4224 + 7 * 528 + lidx];
        float* po = out + obase0 + 5 * 16;
        *reinterpret_cast<float4*>(po)      = q0;
        *reinterpret_cast<float4*>(po + 4)  = q1;
        *reinterpret_cast<float4*>(po + 8)  = q2;
        *reinterpret_cast<float4*>(po + 12) = q3;
    }
}

extern "C" void kernel_launch(void* const* d_in, const int* in_sizes, int n_in,
                              void* d_out, int out_size, void* d_ws, size_t ws_size,
                              hipStream_t stream) {
    const float* x     = (const float*)d_in[0];
    const float* w_sr  = (const float*)d_in[1];
    const float* b_sr  = (const float*)d_in[2];
    const float* Wq    = (const float*)d_in[3];
    const float* bq    = (const float*)d_in[4];
    const float* Wkv   = (const float*)d_in[5];
    const float* bkv   = (const float*)d_in[6];
    const float* gamma = (const float*)d_in[7];
    const float* beta  = (const float*)d_in[8];
    float* out = (float*)d_out;

    unsigned short* qb = (unsigned short*)d_ws;
    unsigned short* kb = qb + (size_t)50331648;
    unsigned short* vb = kb + (size_t)50331648;

    proj_mfma<<<1536, 1024, 0, stream>>>(x, w_sr, b_sr, Wq, bq, Wkv, bkv, qb, kb, vb);

    attn_kernel<<<1024, 512, 0, stream>>>(qb, kb, vb, gamma, beta, out);
}

// Round 18
// 274.873 us; speedup vs baseline: 1.4019x; 1.0347x over previous
//
#include <hip/hip_runtime.h>
#include <stdint.h>
#include <stddef.h>

typedef __attribute__((ext_vector_type(8))) short short8;
typedef __attribute__((ext_vector_type(4))) float f32x4;

// ---- sizes ----
// x: (8, 64, 32, 32, 96) f32.  NH=4, hd=16, scale = 0.25
// intermediates q,k,v: bf16, per (b,o): d-plane layout [d=0..95][pos=h*32+w] (2KB planes)
#define PER_BO 98304            // 96 d * 1024 pos ushorts per (b,o)

__device__ __forceinline__ unsigned int cvtpk(float lo, float hi) {
    unsigned int r;
    asm("v_cvt_pk_bf16_f32 %0, %1, %2" : "=v"(r) : "v"(lo), "v"(hi));
    return r;
}

// ============================ Kernel 1: projection GEMM (MFMA) ============================
// (verbatim R16: aligned A-loads, XOR-swizzled Cb, lgkm-only barriers)
__global__ __launch_bounds__(1024, 4) void proj_mfma(
    const float* __restrict__ x, const float* __restrict__ w_sr, const float* __restrict__ b_sr,
    const float* __restrict__ Wq, const float* __restrict__ bq,
    const float* __restrict__ Wkv, const float* __restrict__ bkv,
    unsigned short* __restrict__ qb, unsigned short* __restrict__ kb, unsigned short* __restrict__ vb)
{
    __shared__ unsigned short Wh[12288];
    __shared__ float bl[192];
    __shared__ unsigned short Cb[2 * 8256];   // [buf][o_l: stride 516][m: 512], dd swizzled

    int t = threadIdx.x;
    int bidx = blockIdx.x;
    int b = bidx & 7;                  // XCD = b
    int lf = bidx >> 3;                // 0..191
    int hrow = lf / 6;
    int dg = lf - hrow * 6;            // 0..5, d-group of 16

    int lane = t & 63;
    int wvi = t >> 6;                  // 0..15; wave owns w = wvi*2, wvi*2+1
    int lr = lane & 15, hk = lane >> 4;

    const float* xb = x + (size_t)b * 6291456 + hrow * 3072 + dg * 16;
    float af[2][16];
#pragma unroll
    for (int pi = 0; pi < 2; ++pi) {
        int w = wvi * 2 + pi;
        const float* xp = xb + (size_t)(hk * 8) * 98304 + w * 96 + lr;
#pragma unroll
        for (int j = 0; j < 8; ++j) {
            af[pi][j]     = xp[(size_t)j * 98304];
            af[pi][8 + j] = xp[(size_t)(32 + j) * 98304];
        }
    }

#pragma unroll
    for (int i = 0; i < 3; ++i) {
        int qi = t + i * 1024;
        int o = qi >> 4;
        int cq = qi & 15;
        int c = cq * 4;
        float4 wv4;
        if (o < 64) wv4 = *reinterpret_cast<const float4*>(Wq + o * 64 + c);
        else {
            wv4 = *reinterpret_cast<const float4*>(Wkv + (o - 64) * 64 + c);
            float4 sr = *reinterpret_cast<const float4*>(w_sr + c);
            wv4.x *= sr.x; wv4.y *= sr.y; wv4.z *= sr.z; wv4.w *= sr.w;
        }
        uint2 pk; pk.x = cvtpk(wv4.x, wv4.y); pk.y = cvtpk(wv4.z, wv4.w);
        int sw = (cq >> 1) ^ (o & 7);
        *reinterpret_cast<uint2*>(&Wh[o * 64 + sw * 8 + (cq & 1) * 4]) = pk;
    }
    if (t < 192) {
        float s;
        if (t < 64) s = bq[t];
        else {
            s = bkv[t - 64];
            for (int c = 0; c < 64; ++c) s += Wkv[(t - 64) * 64 + c] * b_sr[c];
        }
        bl[t] = s;
    }
    __syncthreads();

    short8 ahf[2][2], alf[2][2];
#pragma unroll
    for (int pi = 0; pi < 2; ++pi) {
#pragma unroll
        for (int half = 0; half < 2; ++half) {
            union { unsigned int u[4]; short8 v; } H, L;
#pragma unroll
            for (int q = 0; q < 4; ++q) {
                float f0 = af[pi][half * 8 + 2 * q];
                float f1 = af[pi][half * 8 + 2 * q + 1];
                unsigned int hp = cvtpk(f0, f1);
                float h0 = __uint_as_float(hp << 16);
                float h1 = __uint_as_float(hp & 0xffff0000u);
                H.u[q] = hp;
                L.u[q] = cvtpk(f0 - h0, f1 - h1);
            }
            ahf[pi][half] = H.v; alf[pi][half] = L.v;
        }
    }

    int wo[2];
#pragma unroll
    for (int pi = 0; pi < 2; ++pi) {
        int w = wvi * 2 + pi;
        wo[pi] = lr * 516 + w * 16 + ((hk * 4) ^ (((w >> 2) & 3) << 2));
    }

    int o_l = t >> 6;
    int dd  = (t >> 2) & 15;
    int w8  = t & 3;
    size_t so_po = (size_t)o_l * PER_BO + (size_t)(dg * 16 + dd) * 1024 + hrow * 32 + w8 * 8;
    int so_base = o_l * 516 + w8 * 128;

    float biasv[12];
#pragma unroll
    for (int ot = 0; ot < 12; ++ot) biasv[ot] = bl[ot * 16 + lr];

    f32x4 zero4 = {0.f, 0.f, 0.f, 0.f};
    int s7 = lr & 7;

#pragma unroll
    for (int ot = 0; ot < 12; ++ot) {
        unsigned short* cb = Cb + (ot & 1) * 8256;
        {
            int o = ot * 16 + lr;
            const unsigned short* wr = &Wh[o * 64];
            short8 b0 = *reinterpret_cast<const short8*>(wr + ((hk ^ s7) * 8));
            short8 b1 = *reinterpret_cast<const short8*>(wr + (((hk + 4) ^ s7) * 8));
            float bo = biasv[ot];
#pragma unroll
            for (int pi = 0; pi < 2; ++pi) {
                f32x4 acc = __builtin_amdgcn_mfma_f32_16x16x32_bf16(ahf[pi][0], b0, zero4, 0, 0, 0);
                acc = __builtin_amdgcn_mfma_f32_16x16x32_bf16(ahf[pi][1], b1, acc, 0, 0, 0);
                acc = __builtin_amdgcn_mfma_f32_16x16x32_bf16(alf[pi][0], b0, acc, 0, 0, 0);
                acc = __builtin_amdgcn_mfma_f32_16x16x32_bf16(alf[pi][1], b1, acc, 0, 0, 0);
                uint2 st;
                st.x = cvtpk(acc[0] + bo, acc[1] + bo);
                st.y = cvtpk(acc[2] + bo, acc[3] + bo);
                *reinterpret_cast<uint2*>(&cb[wo[pi]]) = st;
            }
        }
        asm volatile("s_waitcnt lgkmcnt(0)" ::: "memory");
        __builtin_amdgcn_s_barrier();
        {
            int sel = ot >> 2;
            unsigned short* base =
                (sel == 0 ? qb : (sel == 1 ? kb : vb)) + (size_t)(b * 64 + (ot & 3) * 16) * PER_BO;
            union { unsigned short e[8]; uint4 v; } pk;
#pragma unroll
            for (int k = 0; k < 8; ++k)
                pk.e[k] = cb[so_base + k * 16 + (dd ^ ((((w8 << 1) + (k >> 2)) & 3) << 2))];
            *reinterpret_cast<uint4*>(base + so_po) = pk.v;
        }
    }
}

// ============================ Kernel 2: attention (direct-reg, d-planes, paired-sector out) ============================
// R17 structure + deferred out stores: flush gathers 16 floats per pair but stores only on
// odd pair-index, emitting BOTH halves back-to-back (8 contiguous float4 = full 128B sectors)
// -> kills the 1.37x write amplification from half-sector stores an iteration apart.
__global__ __launch_bounds__(512, 4) void attn_kernel(
    const unsigned short* __restrict__ qb, const unsigned short* __restrict__ kb,
    const unsigned short* __restrict__ vb,
    const float* __restrict__ gamma, const float* __restrict__ beta,
    float* __restrict__ out)
{
    __shared__ char smem[52224];
    unsigned short* Vw = (unsigned short*)smem;            // per-wave [w:32][h: stride 36], 18432 B
    float* Osf  = (float*)(smem + 18432);                  // 2 bufs x 8 planes x 528 = 33792 B
    float* lred = (float*)(smem + 18432);                  // aliases Osf (pass1 only)
    float* rlb  = (float*)(smem + 18432 + 16896);

    int t = threadIdx.x;
    int l = t & 63;
    int dsub = t >> 6;
    int lr = l & 15, hk = l >> 4;

    // XCD pair swizzle (both halves of (b,oc) on same XCD, concurrent)
    int id = blockIdx.x;
    int xcd = id & 7;
    int k7 = id >> 3;
    int p = xcd + 8 * (k7 >> 1);
    int half = k7 & 1;
    int oc = p & 63;
    int b = p >> 6;
    int n = oc >> 4;

    const unsigned short* qp = qb + (size_t)(b * 64 + oc) * PER_BO;
    const unsigned short* kp = kb + (size_t)(b * 64 + oc) * PER_BO;
    const unsigned short* vp = vb + (size_t)(b * 64 + oc) * PER_BO;

    float gm = gamma[n], bt = beta[n];
    float decv[8];
#pragma unroll
    for (int gb = 0; gb < 2; ++gb)
#pragma unroll
        for (int r = 0; r < 4; ++r) {
            int hh = half * 16 + hk * 4 + r;
            int gg = gb * 16 + lr;
            float dc = 2.0f * fabsf((float)(hh - gg)) * gm + bt;
            float sp = fmaxf(dc, 0.0f) + log1pf(__expf(-fabsf(dc)));
            decv[gb * 4 + r] = __expf(-sp);
        }

    const float scale = 0.25f;
    f32x4 zero4 = {0.f, 0.f, 0.f, 0.f};

    unsigned int ep[48];
    float lacc[8] = {0.f, 0.f, 0.f, 0.f, 0.f, 0.f, 0.f, 0.f};

    // ---------------- PASS 1: direct-reg QK^T -> E + partial l (no LDS, no barriers) ----------------
    int qoff  = half * 512 + lr * 32 + hk * 8;
    int koff0 = lr * 32 + hk * 8;
    int koff1 = koff0 + 512;

    uint4 qv[2], k0v[2], k1v[2];
    {
        int b0p = dsub * 1024;
        qv[0]  = *reinterpret_cast<const uint4*>(qp + b0p + qoff);
        k0v[0] = *reinterpret_cast<const uint4*>(kp + b0p + koff0);
        k1v[0] = *reinterpret_cast<const uint4*>(kp + b0p + koff1);
        int b1p = (8 + dsub) * 1024;
        qv[1]  = *reinterpret_cast<const uint4*>(qp + b1p + qoff);
        k0v[1] = *reinterpret_cast<const uint4*>(kp + b1p + koff0);
        k1v[1] = *reinterpret_cast<const uint4*>(kp + b1p + koff1);
    }

#pragma unroll
    for (int ch = 0; ch < 12; ++ch) {
        int s = ch & 1;
        union { uint4 u; short8 v; } A, B0, B1;
        A.u = qv[s]; B0.u = k0v[s]; B1.u = k1v[s];
        f32x4 s0 = __builtin_amdgcn_mfma_f32_16x16x32_bf16(A.v, B0.v, zero4, 0, 0, 0);
        f32x4 s1 = __builtin_amdgcn_mfma_f32_16x16x32_bf16(A.v, B1.v, zero4, 0, 0, 0);
        if (ch < 10) {
            int bp = ((ch + 2) * 8 + dsub) * 1024;
            qv[s]  = *reinterpret_cast<const uint4*>(qp + bp + qoff);
            k0v[s] = *reinterpret_cast<const uint4*>(kp + bp + koff0);
            k1v[s] = *reinterpret_cast<const uint4*>(kp + bp + koff1);
        }
        float e[8];
#pragma unroll
        for (int r = 0; r < 4; ++r) {
            e[r]     = __expf(s0[r] * scale + decv[r]);
            e[4 + r] = __expf(s1[r] * scale + decv[4 + r]);
        }
#pragma unroll
        for (int i = 0; i < 8; ++i) lacc[i] += e[i];
        ep[ch * 4 + 0] = cvtpk(e[0], e[1]);
        ep[ch * 4 + 1] = cvtpk(e[2], e[3]);
        ep[ch * 4 + 2] = cvtpk(e[4], e[5]);
        ep[ch * 4 + 3] = cvtpk(e[6], e[7]);
    }

    // ---------------- l reduction (only cross-wave communication) ----------------
#pragma unroll
    for (int i = 0; i < 8; ++i)
        lred[dsub * 528 + (hk * 4 + (i & 3)) * 33 + (i >> 2) * 16 + lr] = lacc[i];
    __syncthreads();
    {
        float rsum = 0.f;
#pragma unroll
        for (int s = 0; s < 8; ++s) rsum += lred[s * 528 + (t >> 5) * 33 + (t & 31)];
        rlb[(t >> 5) * 33 + (t & 31)] = 1.0f / rsum;
    }
    __syncthreads();
    float rl8[8];
#pragma unroll
    for (int i = 0; i < 8; ++i)
        rl8[i] = rlb[(hk * 4 + (i & 3)) * 33 + (i >> 2) * 16 + lr];
    __syncthreads();

    // ---------------- PASS 2: wave-private V stage + P (aliased in Osf) -> PV -> out ----------------
    int vgoff = l * 16;
    int vwbase = dsub * 1152 + ((l & 1) * 16) * 36 + (l >> 1);

    uint4 vv0[2], vv1[2];
    {
        int b0p = dsub * 1024 + vgoff;
        vv0[0] = *reinterpret_cast<const uint4*>(vp + b0p);
        vv1[0] = *reinterpret_cast<const uint4*>(vp + b0p + 8);
        int b1p = (8 + dsub) * 1024 + vgoff;
        vv0[1] = *reinterpret_cast<const uint4*>(vp + b1p);
        vv1[1] = *reinterpret_cast<const uint4*>(vp + b1p + 8);
    }

    size_t obase0 = ((size_t)(b * 64 + oc) * 1024 + half * 512 + t) * 96;
    int lidx = (t >> 5) * 33 + (t & 31);
    float4 h0, h1, h2, h3;   // stash of even-pair flush (stored with odd pair as full sectors)

#pragma unroll
    for (int ch = 0; ch < 12; ++ch) {
        int s = ch & 1;
        // flush previous ch-pair at the start of each even ch (both Osf bufs complete)
        if (s == 0 && ch >= 2) {
            __syncthreads();
            float4 q0, q1, q2, q3;
            q0.x = Osf[0 * 528 + lidx]; q0.y = Osf[1 * 528 + lidx];
            q0.z = Osf[2 * 528 + lidx]; q0.w = Osf[3 * 528 + lidx];
            q1.x = Osf[4 * 528 + lidx]; q1.y = Osf[5 * 528 + lidx];
            q1.z = Osf[6 * 528 + lidx]; q1.w = Osf[7 * 528 + lidx];
            q2.x = Osf[4224 + 0 * 528 + lidx]; q2.y = Osf[4224 + 1 * 528 + lidx];
            q2.z = Osf[4224 + 2 * 528 + lidx]; q2.w = Osf[4224 + 3 * 528 + lidx];
            q3.x = Osf[4224 + 4 * 528 + lidx]; q3.y = Osf[4224 + 5 * 528 + lidx];
            q3.z = Osf[4224 + 6 * 528 + lidx]; q3.w = Osf[4224 + 7 * 528 + lidx];
            int pj = (ch >> 1) - 1;
            if ((pj & 1) == 0) { h0 = q0; h1 = q1; h2 = q2; h3 = q3; }
            else {
                float* po = out + obase0 + (pj - 1) * 16;   // 128B-aligned, 2 full sectors
                *reinterpret_cast<float4*>(po)      = h0;
                *reinterpret_cast<float4*>(po + 4)  = h1;
                *reinterpret_cast<float4*>(po + 8)  = h2;
                *reinterpret_cast<float4*>(po + 12) = h3;
                *reinterpret_cast<float4*>(po + 16) = q0;
                *reinterpret_cast<float4*>(po + 20) = q1;
                *reinterpret_cast<float4*>(po + 24) = q2;
                *reinterpret_cast<float4*>(po + 28) = q3;
            }
            __syncthreads();
        }
        // stage V-plane transposed into wave-private Vw
        {
            union { uint4 u; unsigned short e[8]; } V0, V1;
            V0.u = vv0[s]; V1.u = vv1[s];
#pragma unroll
            for (int i = 0; i < 8; ++i) Vw[vwbase + i * 36] = V0.e[i];
#pragma unroll
            for (int i = 0; i < 8; ++i) Vw[vwbase + (i + 8) * 36] = V1.e[i];
        }
        // build P into the wave's own Osf[s] plane head (consumed before the O-write)
        unsigned short* Pw = (unsigned short*)(Osf + s * 4224 + dsub * 528);
#pragma unroll
        for (int gb = 0; gb < 2; ++gb)
#pragma unroll
            for (int rp = 0; rp < 2; ++rp) {
                unsigned int u = ep[ch * 4 + gb * 2 + rp];
                float p0 = __uint_as_float(u << 16)         * rl8[gb * 4 + rp * 2];
                float p1 = __uint_as_float(u & 0xffff0000u) * rl8[gb * 4 + rp * 2 + 1];
                unsigned int pk = cvtpk(p0, p1);
                Pw[(hk * 4 + rp * 2) * 36 + gb * 16 + lr]     = (unsigned short)pk;
                Pw[(hk * 4 + rp * 2 + 1) * 36 + gb * 16 + lr] = (unsigned short)(pk >> 16);
            }
        if (ch < 10) {
            int bp = ((ch + 2) * 8 + dsub) * 1024 + vgoff;
            vv0[s] = *reinterpret_cast<const uint4*>(vp + bp);
            vv1[s] = *reinterpret_cast<const uint4*>(vp + bp + 8);
        }
        asm volatile("s_waitcnt lgkmcnt(0)" ::: "memory");
        __builtin_amdgcn_sched_barrier(0);
        short8 pa  = *reinterpret_cast<const short8*>(Pw + lr * 36 + hk * 8);
        short8 vb0 = *reinterpret_cast<const short8*>(Vw + dsub * 1152 + lr * 36 + hk * 8);
        short8 vb1 = *reinterpret_cast<const short8*>(Vw + dsub * 1152 + (16 + lr) * 36 + hk * 8);
        f32x4 o0 = __builtin_amdgcn_mfma_f32_16x16x32_bf16(pa, vb0, zero4, 0, 0, 0);
        f32x4 o1 = __builtin_amdgcn_mfma_f32_16x16x32_bf16(pa, vb1, zero4, 0, 0, 0);
        float* Od = Osf + s * 4224 + dsub * 528;
#pragma unroll
        for (int r = 0; r < 4; ++r) {
            Od[(hk * 4 + r) * 33 + lr]      = o0[r];
            Od[(hk * 4 + r) * 33 + 16 + lr] = o1[r];
        }
    }
    // final pair (5): gather + store with stashed pair 4 (full sectors)
    {
        __syncthreads();
        float4 q0, q1, q2, q3;
        q0.x = Osf[0 * 528 + lidx]; q0.y = Osf[1 * 528 + lidx];
        q0.z = Osf[2 * 528 + lidx]; q0.w = Osf[3 * 528 + lidx];
        q1.x = Osf[4 * 528 + lidx]; q1.y = Osf[5 * 528 + lidx];
        q1.z = Osf[6 * 528 + lidx]; q1.w = Osf[7 * 528 + lidx];
        q2.x = Osf[4224 + 0 * 528 + lidx]; q2.y = Osf[4224 + 1 * 528 + lidx];
        q2.z = Osf[4224 + 2 * 528 + lidx]; q2.w = Osf[4224 + 3 * 528 + lidx];
        q3.x = Osf[4224 + 4 * 528 + lidx]; q3.y = Osf[4224 + 5 * 528 + lidx];
        q3.z = Osf[4224 + 6 * 528 + lidx]; q3.w = Osf[4224 + 7 * 528 + lidx];
        float* po = out + obase0 + 4 * 16;
        *reinterpret_cast<float4*>(po)      = h0;
        *reinterpret_cast<float4*>(po + 4)  = h1;
        *reinterpret_cast<float4*>(po + 8)  = h2;
        *reinterpret_cast<float4*>(po + 12) = h3;
        *reinterpret_cast<float4*>(po + 16) = q0;
        *reinterpret_cast<float4*>(po + 20) = q1;
        *reinterpret_cast<float4*>(po + 24) = q2;
        *reinterpret_cast<float4*>(po + 28) = q3;
    }
}

extern "C" void kernel_launch(void* const* d_in, const int* in_sizes, int n_in,
                              void* d_out, int out_size, void* d_ws, size_t ws_size,
                              hipStream_t stream) {
    const float* x     = (const float*)d_in[0];
    const float* w_sr  = (const float*)d_in[1];
    const float* b_sr  = (const float*)d_in[2];
    const float* Wq    = (const float*)d_in[3];
    const float* bq    = (const float*)d_in[4];
    const float* Wkv   = (const float*)d_in[5];
    const float* bkv   = (const float*)d_in[6];
    const float* gamma = (const float*)d_in[7];
    const float* beta  = (const float*)d_in[8];
    float* out = (float*)d_out;

    unsigned short* qb = (unsigned short*)d_ws;
    unsigned short* kb = qb + (size_t)50331648;
    unsigned short* vb = kb + (size_t)50331648;

    proj_mfma<<<1536, 1024, 0, stream>>>(x, w_sr, b_sr, Wq, bq, Wkv, bkv, qb, kb, vb);

    attn_kernel<<<1024, 512, 0, stream>>>(qb, kb, vb, gamma, beta, out);
}